// Round 4
// baseline (388.947 us; speedup 1.0000x reference)
//
#include <hip/hip_runtime.h>

#define N_NODES 100000
#define N_EDGES 800000
#define DIM 128

#define NB 391        // buckets of 256 dst nodes
#define BKCAP 2560    // per-bucket window; mean 2046, +11 sigma margin
#define EPB 2048      // edges per bin block
#define BINB ((N_EDGES + EPB - 1) / EPB)  // 391
#define NXF (N_NODES * DIM / 4)           // 3.2M float4 quads in x
#define WF4 (4 * 4096)                    // 4 weight mats, 4096 float4 each
#define NBLK ((N_NODES + 127) / 128)      // 782 fused blocks, 128 rows each

typedef __attribute__((ext_vector_type(8))) short short8;
typedef __attribute__((ext_vector_type(4))) float float4v;
typedef __attribute__((ext_vector_type(2))) float float2v;
typedef __attribute__((ext_vector_type(4))) unsigned int uint4v;
typedef __attribute__((ext_vector_type(2))) unsigned int uint2v;

__device__ __forceinline__ float lo16(unsigned int v) {
    return __uint_as_float(v << 16);
}
__device__ __forceinline__ float hi16(unsigned int v) {
    return __uint_as_float(v & 0xffff0000u);
}
__device__ __forceinline__ float2v unp(unsigned int v) {
    return (float2v){lo16(v), hi16(v)};
}
__device__ __forceinline__ unsigned short f2bf(float f) {
    unsigned int x = __float_as_uint(f);
    unsigned int r = x + 0x7fffu + ((x >> 16) & 1u);  // RNE
    return (unsigned short)(r >> 16);
}
__device__ __forceinline__ unsigned int packbf(float a, float b) {
    return (unsigned int)f2bf(a) | ((unsigned int)f2bf(b) << 16);
}

// wave-inclusive scan over 64 lanes (6 shfl_up, barrier-free)
__device__ __forceinline__ int wave_iscan(int x, int lane) {
#pragma unroll
    for (int off = 1; off < 64; off <<= 1) {
        int n = __shfl_up(x, off, 64);
        x += (lane >= off) ? n : 0;
    }
    return x;
}

// ---- CSR build helpers ------------------------------------------------------

__device__ __forceinline__ void load_edge(const int* __restrict__ edge, int eflag, int e,
                                          int& s, int& d) {
    if (eflag == 0) {  // int64 little-endian: low word holds the value
        s = edge[2 * e];
        d = edge[2 * (N_EDGES + e)];
    } else {
        s = edge[e];
        d = edge[N_EDGES + e];
    }
}

// ---- fused bin + conv -------------------------------------------------------
// Blocks < BINB: bin 2048 edges via LDS histogram -> one global atomic range
// reservation per bucket -> scatter pairs=(src<<8|dst&255) into bucket window.
// Layout detect is per-wave (barrier-free): sample 64 odd dwords of the int64
// view of this block's edge range; any nonzero => int32 layout.
// Blocks >= BINB: fp32 -> packed-bf16 conversion of x then 4 weight matrices.

__global__ __launch_bounds__(256) void binconv_kernel(
    const int* __restrict__ edge, int* __restrict__ cur,
    unsigned int* __restrict__ pairs, const float* __restrict__ x,
    const float* __restrict__ wa, const float* __restrict__ wb,
    const float* __restrict__ wc, const float* __restrict__ wd,
    unsigned int* __restrict__ xdst, unsigned int* __restrict__ wdst) {
    int t = threadIdx.x;
    if (blockIdx.x >= BINB) {  // ---- conv part
        int i = (blockIdx.x - BINB) * 256 + t;  // float4 index
        if (i < NXF) {
            float4 v = ((const float4*)x)[i];
            uint2v o = {packbf(v.x, v.y), packbf(v.z, v.w)};
            *(uint2v*)(xdst + 2 * (size_t)i) = o;
        } else {
            int j = i - NXF;
            if (j < WF4) {
                int m = j >> 12, r = j & 4095;
                const float* src = (m == 0) ? wa : (m == 1) ? wb : (m == 2) ? wc : wd;
                float4 v = ((const float4*)src)[r];
                uint2v o = {packbf(v.x, v.y), packbf(v.z, v.w)};
                *(uint2v*)(wdst + (size_t)m * 8192 + 2 * r) = o;
            }
        }
        return;
    }
    // ---- bin part
    __shared__ int lcnt[NB];
    __shared__ int lbase[NB];
    for (int i = t; i < NB; i += 256) lcnt[i] = 0;
    int e0 = blockIdx.x * EPB;
    // per-wave layout probe (no barrier needed; each wave decides identically)
    int eflag = __any(edge[2 * (e0 + t) + 1] != 0) ? 1 : 0;
    __syncthreads();
    int vb[8];
    unsigned int vp[8];
    bool valid[8];
#pragma unroll
    for (int k = 0; k < 8; ++k) {
        int e = e0 + k * 256 + t;
        valid[k] = false;
        if (e < N_EDGES) {
            int s, d;
            load_edge(edge, eflag, e, s, d);
            if ((unsigned)s < N_NODES && (unsigned)d < N_NODES) {
                valid[k] = true;
                vb[k] = d >> 8;
                vp[k] = ((unsigned int)s << 8) | (unsigned int)(d & 255);
                atomicAdd(&lcnt[vb[k]], 1);
            }
        }
    }
    __syncthreads();
    for (int i = t; i < NB; i += 256) {
        int c = lcnt[i];
        lbase[i] = (c > 0) ? atomicAdd(&cur[i], c) : 0;  // range reservation
        lcnt[i] = 0;  // reuse as local cursor
    }
    __syncthreads();
#pragma unroll
    for (int k = 0; k < 8; ++k) {
        if (valid[k]) {
            int b = vb[k];
            int pos = lbase[b] + atomicAdd(&lcnt[b], 1);
            if (pos < BKCAP)  // statistically unreachable guard
                pairs[(size_t)b * BKCAP + pos] = vp[k];
        }
    }
}

// ---- csr v2: shuffle-scan bucket prefix + per-bucket histogram/scatter ------

__global__ __launch_bounds__(256) void csr_kernel(const int* __restrict__ cur,
                                                  const unsigned int* __restrict__ pairs,
                                                  int* __restrict__ rowptr,
                                                  int* __restrict__ esrc) {
    __shared__ int sh[512];
    __shared__ int hist[256];
    __shared__ int wsum[8];
    int b = blockIdx.x, t = threadIdx.x;
    int lane = t & 63, wv = t >> 6;
    // inclusive scan of 391 bucket totals: 2 elems/thread, wave scan + combine
    int e0 = 2 * t, e1 = 2 * t + 1;
    int v0 = (e0 < NB) ? min(cur[e0], BKCAP) : 0;
    int v1 = (e1 < NB) ? min(cur[e1], BKCAP) : 0;
    int p = wave_iscan(v0 + v1, lane);
    if (lane == 63) wsum[wv] = p;
    hist[t] = 0;  // init for the histogram phase (shares the barrier below)
    __syncthreads();
    int wpre = 0;
#pragma unroll
    for (int w = 0; w < 4; ++w) wpre += (w < wv) ? wsum[w] : 0;
    int incl1 = wpre + p;  // inclusive prefix at elem e1
    sh[e0] = incl1 - v1;   // inclusive at e0
    sh[e1] = incl1;
    __syncthreads();
    int n = min(cur[b], BKCAP);
    int base = sh[b] - n;  // exclusive prefix of bucket b
    if (b == 0 && t == 0) rowptr[N_NODES] = sh[NB - 1];
    // local histogram of dst low-byte
    const unsigned int* pp = pairs + (size_t)b * BKCAP;
    for (int i = t; i < n; i += 256) atomicAdd(&hist[pp[i] & 255u], 1);
    __syncthreads();
    int v = hist[t];
    int ix = wave_iscan(v, lane);
    if (lane == 63) wsum[4 + wv] = ix;
    __syncthreads();
    int wpre2 = 0;
#pragma unroll
    for (int w = 0; w < 4; ++w) wpre2 += (w < wv) ? wsum[4 + w] : 0;
    int excl = wpre2 + ix - v;  // exclusive prefix of hist[t]
    int node = b * 256 + t;
    if (node < N_NODES) rowptr[node] = base + excl;
    hist[t] = excl;  // reuse as per-dst cursors
    __syncthreads();
    for (int i = t; i < n; i += 256) {
        unsigned int pk = pp[i];
        int pos = atomicAdd(&hist[pk & 255u], 1);
        esrc[base + pos] = (int)(pk >> 8);
    }
}

// ---- fused agg + SAGE GEMM v2: max-occupancy (one layer per dispatch) -------
// R3 post-mortem: v1 was latency-bound (hbm 1.6 TB/s = 16 waves/CU x 2 loads
// in flight; Occupancy 31%). Fix: LDS = mean tile ONLY (32 KB) -> 4 blocks/CU
// = 32 waves/CU; W B-frags are read directly from global (W is 32 KB/mat,
// read identically by all 782 blocks -> L1/L2-resident; MfmaUtil was 3%, so
// B latency is hidden). Barriers: 3 -> 1. Grid 782 <= 1024 resident slots.
// Phase A: wave w aggregates nodes [blockRow+w*16, +16); v8 gather (4 edges x
//   16-dim slices, dwordx4), reduce-scatter, bf16 row into swizzled LDS tile.
// Phase B: steps 0-3 A=mean(LDS) B=W0(global); steps 4-7 A=self rows (regs,
//   issued pre-barrier) B=W1(global).
// Epilogue: relu+bf16 store (layer 1) or fused FC dot + 16-lane reduce (layer 2).

template <int FUSE_FC>
__global__ __launch_bounds__(512, 8) void fused_kernel(
    const unsigned int* __restrict__ feat2,   // gather table (xbf or h1), dwords
    const unsigned short* __restrict__ A1g,   // self-term rows (xbf or h1)
    const int* __restrict__ rowptr, const int* __restrict__ esrc,
    const unsigned int* __restrict__ Wpk,     // 2 mats, mat m at dword m*8192
    const float* __restrict__ bias, const float* __restrict__ wfc,
    const float* __restrict__ bfc, unsigned short* __restrict__ hout,
    float* __restrict__ out) {
    __shared__ unsigned int mlds[8192];  // 32 KB: mean tile, 128 rows x 64 dw, swizzled

    int t = threadIdx.x;
    int wave = t >> 6, lane = t & 63;
    int rowgrp = lane >> 4;   // a.k.a. qsel in gemm phase
    int dimgrp = lane & 15;   // a.k.a. lrow in gemm phase
    int blockRow = blockIdx.x * 128;

    // ---- agg phase: wave w -> 16 nodes ----
#pragma unroll 1
    for (int i = 0; i < 16; ++i) {
        int node = blockRow + wave * 16 + i;
        if (node >= N_NODES) break;  // only in last block
        int beg = rowptr[node], end = rowptr[node + 1];
        float2v a0 = {0.f, 0.f}, a1 = {0.f, 0.f}, a2 = {0.f, 0.f}, a3 = {0.f, 0.f};
        int e = beg;
        for (; e + 8 <= end; e += 8) {  // 8 edges/iter: 2 dwordx4 in flight
            int s0 = esrc[e + rowgrp];
            int s1 = esrc[e + 4 + rowgrp];
            uint4v v0 = *(const uint4v*)(feat2 + (size_t)s0 * 64 + dimgrp * 4);
            uint4v v1 = *(const uint4v*)(feat2 + (size_t)s1 * 64 + dimgrp * 4);
            a0 += unp(v0.x) + unp(v1.x);
            a1 += unp(v0.y) + unp(v1.y);
            a2 += unp(v0.z) + unp(v1.z);
            a3 += unp(v0.w) + unp(v1.w);
        }
        if (e < end) {  // unified tail: up to 7 edges, 2 parallel masked loads
            int i0 = e + rowgrp, i1 = e + 4 + rowgrp;
            bool ok0 = i0 < end, ok1 = i1 < end;
            int s0 = esrc[ok0 ? i0 : end - 1];
            int s1 = esrc[ok1 ? i1 : end - 1];
            uint4v v0 = *(const uint4v*)(feat2 + (size_t)s0 * 64 + dimgrp * 4);
            uint4v v1 = *(const uint4v*)(feat2 + (size_t)s1 * 64 + dimgrp * 4);
            float m0 = ok0 ? 1.f : 0.f, m1 = ok1 ? 1.f : 0.f;
            float2v m0v = {m0, m0}, m1v = {m1, m1};
            a0 += m0v * unp(v0.x) + m1v * unp(v1.x);
            a1 += m0v * unp(v0.y) + m1v * unp(v1.y);
            a2 += m0v * unp(v0.z) + m1v * unp(v1.z);
            a3 += m0v * unp(v0.w) + m1v * unp(v1.w);
        }
        // reduce-scatter over rowgrp bits: lane keeps accumulator index == rowgrp.
        float2v s0v = (rowgrp & 1) ? a0 : a1;
        float2v k0v = (rowgrp & 1) ? a1 : a0;
        float2v s2v = (rowgrp & 1) ? a2 : a3;
        float2v k2v = (rowgrp & 1) ? a3 : a2;
        k0v.x += __shfl_xor(s0v.x, 16, 64);
        k0v.y += __shfl_xor(s0v.y, 16, 64);
        k2v.x += __shfl_xor(s2v.x, 16, 64);
        k2v.y += __shfl_xor(s2v.y, 16, 64);
        float2v sv = (rowgrp & 2) ? k0v : k2v;
        float2v kv = (rowgrp & 2) ? k2v : k0v;
        kv.x += __shfl_xor(sv.x, 32, 64);
        kv.y += __shfl_xor(sv.y, 32, 64);
        int deg = end - beg;
        float sc = deg > 0 ? 1.f / (float)deg : 0.f;
        int r = wave * 16 + i;  // LDS row; chunk dimgrp swizzled by row
        mlds[r * 64 + ((dimgrp ^ (r & 15)) << 2) + rowgrp] = packbf(kv.x * sc, kv.y * sc);
    }

    // issue A1 (self-term) global loads early: hidden under barrier + steps 0-3
    int rA = blockRow + wave * 16 + dimgrp;
    if (rA >= N_NODES) rA = N_NODES - 1;  // clamp; masked at store
    short8 aA1[4];
#pragma unroll
    for (int kt = 0; kt < 4; ++kt)
        aA1[kt] = *(const short8*)(A1g + (size_t)rA * DIM + kt * 32 + rowgrp * 8);

    __syncthreads();

    int lrow = dimgrp, qsel = rowgrp;
    float4v acc[8];
#pragma unroll
    for (int nt = 0; nt < 8; ++nt) acc[nt] = (float4v){0.f, 0.f, 0.f, 0.f};

    // ---- steps 0-3: A = mean tile (LDS), B = W0 (global, L1/L2-hot) ----
    const unsigned int* mrow = mlds + (wave * 16 + lrow) * 64;
#pragma unroll
    for (int kt = 0; kt < 4; ++kt) {
        short8 afr = *(const short8*)(mrow + (((kt * 4 + qsel) ^ lrow) << 2));
        int qg = kt * 4 + qsel;
#pragma unroll
        for (int nt = 0; nt < 8; ++nt) {
            short8 b = *(const short8*)(Wpk + (nt * 16 + lrow) * 64 + qg * 4);
            acc[nt] = __builtin_amdgcn_mfma_f32_16x16x32_bf16(afr, b, acc[nt], 0, 0, 0);
        }
    }

    // ---- steps 4-7: A = aA1 (regs), B = W1 (global, L1/L2-hot) ----
#pragma unroll
    for (int kt = 0; kt < 4; ++kt) {
        int qg = kt * 4 + qsel;
#pragma unroll
        for (int nt = 0; nt < 8; ++nt) {
            short8 b = *(const short8*)(Wpk + 8192 + (nt * 16 + lrow) * 64 + qg * 4);
            acc[nt] = __builtin_amdgcn_mfma_f32_16x16x32_bf16(aA1[kt], b, acc[nt], 0, 0, 0);
        }
    }

    // ---- epilogue ----
    int crow0 = qsel * 4;
    if (!FUSE_FC) {
#pragma unroll
        for (int nt = 0; nt < 8; ++nt) {
            int col = nt * 16 + lrow;
            float bv = bias[col];
#pragma unroll
            for (int r4 = 0; r4 < 4; ++r4) {
                int row = blockRow + wave * 16 + crow0 + r4;
                if (row < N_NODES) {
                    float v = acc[nt][r4] + bv;
                    hout[(size_t)row * DIM + col] = f2bf(v > 0.f ? v : 0.f);
                }
            }
        }
    } else {
        float bv[8], wv[8];
#pragma unroll
        for (int nt = 0; nt < 8; ++nt) {
            bv[nt] = bias[nt * 16 + lrow];
            wv[nt] = wfc[nt * 16 + lrow];
        }
        float bf0 = bfc[0];
#pragma unroll
        for (int r4 = 0; r4 < 4; ++r4) {
            float p = 0.f;
#pragma unroll
            for (int nt = 0; nt < 8; ++nt) {
                float v = acc[nt][r4] + bv[nt];
                p += (v > 0.f ? v : 0.f) * wv[nt];
            }
#pragma unroll
            for (int off = 1; off < 16; off <<= 1) p += __shfl_xor(p, off, 64);
            int row = blockRow + wave * 16 + crow0 + r4;
            if (lrow == 0 && row < N_NODES) out[row] = p + bf0;
        }
    }
}

// ---- host glue -------------------------------------------------------------

extern "C" void kernel_launch(void* const* d_in, const int* in_sizes, int n_in,
                              void* d_out, int out_size, void* d_ws, size_t ws_size,
                              hipStream_t stream) {
    const float* x  = (const float*)d_in[0];
    const int* edge = (const int*)d_in[1];
    const float* W1l = (const float*)d_in[2];
    const float* b1  = (const float*)d_in[3];
    const float* W1r = (const float*)d_in[4];
    const float* W2l = (const float*)d_in[5];
    const float* b2  = (const float*)d_in[6];
    const float* W2r = (const float*)d_in[7];
    const float* Wfc = (const float*)d_in[8];
    const float* bfc = (const float*)d_in[9];
    float* out = (float*)d_out;  // fp32 output

    char* ws = (char*)d_ws;
    size_t off = 0;
    int* rowptr = (int*)(ws + off); off += ((size_t)N_NODES + 64) * 4;
    int* esrc   = (int*)(ws + off); off += (size_t)N_EDGES * 4;
    int* cur    = (int*)(ws + off); off += (size_t)NB * 4 + 256;
    off = (off + 255) & ~(size_t)255;
    unsigned int* pairs = (unsigned int*)(ws + off); off += (size_t)NB * BKCAP * 4;
    off = (off + 255) & ~(size_t)255;
    unsigned int* wbf = (unsigned int*)(ws + off); off += 4 * 8192 * 4;
    off = (off + 255) & ~(size_t)255;
    unsigned short* xbf = (unsigned short*)(ws + off); off += (size_t)N_NODES * DIM * 2;
    unsigned short* h1  = (unsigned short*)(ws + off); off += (size_t)N_NODES * DIM * 2;
    // total ~58 MB

    const int convBlocks = (NXF + WF4 + 255) / 256;  // float4 units

    hipMemsetAsync(cur, 0, NB * sizeof(int), stream);
    binconv_kernel<<<BINB + convBlocks, 256, 0, stream>>>(edge, cur, pairs, x,
                                                          W1l, W1r, W2l, W2r,
                                                          (unsigned int*)xbf, wbf);
    csr_kernel<<<NB, 256, 0, stream>>>(cur, pairs, rowptr, esrc);

    // layer 1: agg+gemm fused, W mats 0,1
    fused_kernel<0><<<NBLK, 512, 0, stream>>>((const unsigned int*)xbf, xbf, rowptr,
                                              esrc, wbf, b1, nullptr, nullptr, h1,
                                              nullptr);
    // layer 2 + fused FC: W mats 2,3
    fused_kernel<1><<<NBLK, 512, 0, stream>>>((const unsigned int*)h1, h1, rowptr,
                                              esrc, wbf + 2 * 8192, b2, Wfc, bfc,
                                              nullptr, out);
}

// Round 5
// 322.504 us; speedup vs baseline: 1.2060x; 1.2060x over previous
//
#include <hip/hip_runtime.h>

#define N_NODES 100000
#define N_EDGES 800000
#define DIM 128

#define NB 391        // buckets of 256 dst nodes
#define BKCAP 2560    // per-bucket window; mean 2046, +11 sigma margin
#define EPB 2048      // edges per bin block
#define BINB ((N_EDGES + EPB - 1) / EPB)  // 391
#define NXF (N_NODES * DIM / 4)           // 3.2M float4 quads in x
#define WF4 (4 * 4096)                    // 4 weight mats, 4096 float4 each

typedef __attribute__((ext_vector_type(8))) short short8;
typedef __attribute__((ext_vector_type(4))) float float4v;
typedef __attribute__((ext_vector_type(2))) float float2v;
typedef __attribute__((ext_vector_type(4))) unsigned int uint4v;
typedef __attribute__((ext_vector_type(2))) unsigned int uint2v;

__device__ __forceinline__ float lo16(unsigned int v) {
    return __uint_as_float(v << 16);
}
__device__ __forceinline__ float hi16(unsigned int v) {
    return __uint_as_float(v & 0xffff0000u);
}
__device__ __forceinline__ float2v unp(unsigned int v) {
    return (float2v){lo16(v), hi16(v)};
}
__device__ __forceinline__ unsigned short f2bf(float f) {
    unsigned int x = __float_as_uint(f);
    unsigned int r = x + 0x7fffu + ((x >> 16) & 1u);  // RNE
    return (unsigned short)(r >> 16);
}
__device__ __forceinline__ unsigned int packbf(float a, float b) {
    return (unsigned int)f2bf(a) | ((unsigned int)f2bf(b) << 16);
}

// wave-inclusive scan over 64 lanes (6 shfl_up, barrier-free)
__device__ __forceinline__ int wave_iscan(int x, int lane) {
#pragma unroll
    for (int off = 1; off < 64; off <<= 1) {
        int n = __shfl_up(x, off, 64);
        x += (lane >= off) ? n : 0;
    }
    return x;
}

// ---- CSR build helpers ------------------------------------------------------

__device__ __forceinline__ void load_edge(const int* __restrict__ edge, int eflag, int e,
                                          int& s, int& d) {
    if (eflag == 0) {  // int64 little-endian: low word holds the value
        s = edge[2 * e];
        d = edge[2 * (N_EDGES + e)];
    } else {
        s = edge[e];
        d = edge[N_EDGES + e];
    }
}

// ---- fused bin + conv -------------------------------------------------------
// Blocks < BINB: bin 2048 edges via LDS histogram -> one global atomic range
// reservation per bucket -> scatter pairs=(src<<8|dst&255) into bucket window.
// Layout detect is per-wave (barrier-free): sample 64 odd dwords of the int64
// view of this block's edge range; any nonzero => int32 layout.
// Blocks >= BINB: fp32 -> packed-bf16 conversion of x then 4 weight matrices.

__global__ __launch_bounds__(256) void binconv_kernel(
    const int* __restrict__ edge, int* __restrict__ cur,
    unsigned int* __restrict__ pairs, const float* __restrict__ x,
    const float* __restrict__ wa, const float* __restrict__ wb,
    const float* __restrict__ wc, const float* __restrict__ wd,
    unsigned int* __restrict__ xdst, unsigned int* __restrict__ wdst) {
    int t = threadIdx.x;
    if (blockIdx.x >= BINB) {  // ---- conv part
        int i = (blockIdx.x - BINB) * 256 + t;  // float4 index
        if (i < NXF) {
            float4 v = ((const float4*)x)[i];
            uint2v o = {packbf(v.x, v.y), packbf(v.z, v.w)};
            *(uint2v*)(xdst + 2 * (size_t)i) = o;
        } else {
            int j = i - NXF;
            if (j < WF4) {
                int m = j >> 12, r = j & 4095;
                const float* src = (m == 0) ? wa : (m == 1) ? wb : (m == 2) ? wc : wd;
                float4 v = ((const float4*)src)[r];
                uint2v o = {packbf(v.x, v.y), packbf(v.z, v.w)};
                *(uint2v*)(wdst + (size_t)m * 8192 + 2 * r) = o;
            }
        }
        return;
    }
    // ---- bin part
    __shared__ int lcnt[NB];
    __shared__ int lbase[NB];
    for (int i = t; i < NB; i += 256) lcnt[i] = 0;
    int e0 = blockIdx.x * EPB;
    // per-wave layout probe (no barrier needed; each wave decides identically)
    int eflag = __any(edge[2 * (e0 + t) + 1] != 0) ? 1 : 0;
    __syncthreads();
    int vb[8];
    unsigned int vp[8];
    bool valid[8];
#pragma unroll
    for (int k = 0; k < 8; ++k) {
        int e = e0 + k * 256 + t;
        valid[k] = false;
        if (e < N_EDGES) {
            int s, d;
            load_edge(edge, eflag, e, s, d);
            if ((unsigned)s < N_NODES && (unsigned)d < N_NODES) {
                valid[k] = true;
                vb[k] = d >> 8;
                vp[k] = ((unsigned int)s << 8) | (unsigned int)(d & 255);
                atomicAdd(&lcnt[vb[k]], 1);
            }
        }
    }
    __syncthreads();
    for (int i = t; i < NB; i += 256) {
        int c = lcnt[i];
        lbase[i] = (c > 0) ? atomicAdd(&cur[i], c) : 0;  // range reservation
        lcnt[i] = 0;  // reuse as local cursor
    }
    __syncthreads();
#pragma unroll
    for (int k = 0; k < 8; ++k) {
        if (valid[k]) {
            int b = vb[k];
            int pos = lbase[b] + atomicAdd(&lcnt[b], 1);
            if (pos < BKCAP)  // statistically unreachable guard
                pairs[(size_t)b * BKCAP + pos] = vp[k];
        }
    }
}

// ---- csr v2: shuffle-scan bucket prefix + per-bucket histogram/scatter ------

__global__ __launch_bounds__(256) void csr_kernel(const int* __restrict__ cur,
                                                  const unsigned int* __restrict__ pairs,
                                                  int* __restrict__ rowptr,
                                                  int* __restrict__ esrc) {
    __shared__ int sh[512];
    __shared__ int hist[256];
    __shared__ int wsum[8];
    int b = blockIdx.x, t = threadIdx.x;
    int lane = t & 63, wv = t >> 6;
    // inclusive scan of 391 bucket totals: 2 elems/thread, wave scan + combine
    int e0 = 2 * t, e1 = 2 * t + 1;
    int v0 = (e0 < NB) ? min(cur[e0], BKCAP) : 0;
    int v1 = (e1 < NB) ? min(cur[e1], BKCAP) : 0;
    int p = wave_iscan(v0 + v1, lane);
    if (lane == 63) wsum[wv] = p;
    hist[t] = 0;  // init for the histogram phase (shares the barrier below)
    __syncthreads();
    int wpre = 0;
#pragma unroll
    for (int w = 0; w < 4; ++w) wpre += (w < wv) ? wsum[w] : 0;
    int incl1 = wpre + p;  // inclusive prefix at elem e1
    sh[e0] = incl1 - v1;   // inclusive at e0
    sh[e1] = incl1;
    __syncthreads();
    int n = min(cur[b], BKCAP);
    int base = sh[b] - n;  // exclusive prefix of bucket b
    if (b == 0 && t == 0) rowptr[N_NODES] = sh[NB - 1];
    // local histogram of dst low-byte
    const unsigned int* pp = pairs + (size_t)b * BKCAP;
    for (int i = t; i < n; i += 256) atomicAdd(&hist[pp[i] & 255u], 1);
    __syncthreads();
    int v = hist[t];
    int ix = wave_iscan(v, lane);
    if (lane == 63) wsum[4 + wv] = ix;
    __syncthreads();
    int wpre2 = 0;
#pragma unroll
    for (int w = 0; w < 4; ++w) wpre2 += (w < wv) ? wsum[4 + w] : 0;
    int excl = wpre2 + ix - v;  // exclusive prefix of hist[t]
    int node = b * 256 + t;
    if (node < N_NODES) rowptr[node] = base + excl;
    hist[t] = excl;  // reuse as per-dst cursors
    __syncthreads();
    for (int i = t; i < n; i += 256) {
        unsigned int pk = pp[i];
        int pos = atomicAdd(&hist[pk & 255u], 1);
        esrc[base + pos] = (int)(pk >> 8);
    }
}

// ---- mean aggregation v9: grid-stride persistent, rowptr software-pipeline --
// 2048 blocks * 4 waves = 32 waves/CU. At 32 waves/CU this runs ~5.9 TB/s
// effective (R2-R4 decomposition) = random-line service ceiling. Do not lower
// its occupancy (R3 lesson: 16 waves/CU -> 1.6 TB/s).

__global__ __launch_bounds__(256) void agg_kernel(const unsigned int* __restrict__ feat2,
                                                  const int* __restrict__ rowptr,
                                                  const int* __restrict__ esrc,
                                                  unsigned int* __restrict__ meanout) {
    int wid = (blockIdx.x * blockDim.x + threadIdx.x) >> 6;  // global wave id
    int lane = threadIdx.x & 63;
    int rowgrp = lane >> 4;
    int dimgrp = lane & 15;
    const int nwaves = 2048 * 4;
    int node = wid;  // wid < 8192 << N_NODES, always valid
    int beg = rowptr[node], end = rowptr[node + 1];
    while (1) {
        int nn = node + nwaves;
        int nbg = 0, nen = 0;
        if (nn < N_NODES) {  // prefetch next node's rowptr pair (overlaps gathers)
            nbg = rowptr[nn];
            nen = rowptr[nn + 1];
        }
        float2v a0 = {0.f, 0.f}, a1 = {0.f, 0.f}, a2 = {0.f, 0.f}, a3 = {0.f, 0.f};
        int e = beg;
        for (; e + 8 <= end; e += 8) {  // 8 edges/iter: 2 dwordx4 in flight
            int s0 = esrc[e + rowgrp];
            int s1 = esrc[e + 4 + rowgrp];
            uint4v v0 = *(const uint4v*)(feat2 + (size_t)s0 * 64 + dimgrp * 4);
            uint4v v1 = *(const uint4v*)(feat2 + (size_t)s1 * 64 + dimgrp * 4);
            a0 += unp(v0.x) + unp(v1.x);
            a1 += unp(v0.y) + unp(v1.y);
            a2 += unp(v0.z) + unp(v1.z);
            a3 += unp(v0.w) + unp(v1.w);
        }
        if (e < end) {  // unified tail: up to 7 edges, 2 parallel masked loads
            int i0 = e + rowgrp, i1 = e + 4 + rowgrp;
            bool ok0 = i0 < end, ok1 = i1 < end;
            int s0 = esrc[ok0 ? i0 : end - 1];
            int s1 = esrc[ok1 ? i1 : end - 1];
            uint4v v0 = *(const uint4v*)(feat2 + (size_t)s0 * 64 + dimgrp * 4);
            uint4v v1 = *(const uint4v*)(feat2 + (size_t)s1 * 64 + dimgrp * 4);
            float m0 = ok0 ? 1.f : 0.f, m1 = ok1 ? 1.f : 0.f;
            float2v m0v = {m0, m0}, m1v = {m1, m1};
            a0 += m0v * unp(v0.x) + m1v * unp(v1.x);
            a1 += m0v * unp(v0.y) + m1v * unp(v1.y);
            a2 += m0v * unp(v0.z) + m1v * unp(v1.z);
            a3 += m0v * unp(v0.w) + m1v * unp(v1.w);
        }
        // reduce-scatter over rowgrp bits: lane keeps accumulator index == rowgrp.
        float2v s0v = (rowgrp & 1) ? a0 : a1;
        float2v k0v = (rowgrp & 1) ? a1 : a0;
        float2v s2v = (rowgrp & 1) ? a2 : a3;
        float2v k2v = (rowgrp & 1) ? a3 : a2;
        k0v.x += __shfl_xor(s0v.x, 16, 64);
        k0v.y += __shfl_xor(s0v.y, 16, 64);
        k2v.x += __shfl_xor(s2v.x, 16, 64);
        k2v.y += __shfl_xor(s2v.y, 16, 64);
        float2v sv = (rowgrp & 2) ? k0v : k2v;
        float2v kv = (rowgrp & 2) ? k2v : k0v;
        kv.x += __shfl_xor(sv.x, 32, 64);
        kv.y += __shfl_xor(sv.y, 32, 64);
        int deg = end - beg;
        float sc = deg > 0 ? 1.f / (float)deg : 0.f;
        meanout[(size_t)node * 64 + dimgrp * 4 + rowgrp] = packbf(kv.x * sc, kv.y * sc);
        if (nn >= N_NODES) break;
        node = nn;
        beg = nbg;
        end = nen;
    }
}

// ---- SAGE GEMM v6: occupancy-first (R4 post-mortem) -------------------------
// R2's v5 ran at 8 waves/CU (launch_bounds(256,2), acc[4][8]=128 VGPR) and was
// MLP-starved (~32 us vs ~14 us traffic model). v6: 16-row wave tile ->
// acc[8]=32 VGPR; both A-frag sets (mean+self, 8 independent dwordx4) issued
// up-front; W read from global (32 KB/mat, phase-separated -> L1-resident;
// addressing identical to the R3/R4-verified fused kernel). launch_bounds
// (256,4) -> 128-VGPR cap (NO 64-cap: R4 spill lesson) -> 16 waves/CU, 2x v5.
// MFMA C/D: col=lane&15, row=(lane>>4)*4+reg (verified layout).
// FUSE_FC: epilogue out[row] = sum_col relu(h)[col]*wfc[col] + bfc (fp32).

template <int FUSE_FC>
__global__ __launch_bounds__(256, 4) void gemm_kernel(
    const unsigned short* __restrict__ A0,  // mean rows
    const unsigned short* __restrict__ A1,  // self rows (xbf or h1)
    const unsigned int* __restrict__ Wpk,   // 2 matrices, mat m at dword m*8192
    const float* __restrict__ bias, const float* __restrict__ wfc,
    const float* __restrict__ bfc, unsigned short* __restrict__ hout,
    float* __restrict__ out) {
    int t = threadIdx.x;
    int wave = t >> 6, lane = t & 63;
    int lrow = lane & 15;   // A row-in-tile / B col-in-tile / C col
    int qsel = lane >> 4;   // k-octet select
    int rowBase = blockIdx.x * 64 + wave * 16;

    int rA = rowBase + lrow;
    if (rA >= N_NODES) rA = N_NODES - 1;  // clamp; masked at store

    // all 8 A-frags issued before any MFMA: deep MLP on the streaming reads
    short8 am[4], as[4];
#pragma unroll
    for (int kt = 0; kt < 4; ++kt) {
        am[kt] = *(const short8*)(A0 + (size_t)rA * DIM + kt * 32 + qsel * 8);
        as[kt] = *(const short8*)(A1 + (size_t)rA * DIM + kt * 32 + qsel * 8);
    }

    float4v acc[8];
#pragma unroll
    for (int nt = 0; nt < 8; ++nt) acc[nt] = (float4v){0.f, 0.f, 0.f, 0.f};

    // steps 0-3: A = mean, B = W0 (global, L1-hot: 32 KB tile, all waves share)
#pragma unroll
    for (int kt = 0; kt < 4; ++kt) {
        int qg = kt * 4 + qsel;
#pragma unroll
        for (int nt = 0; nt < 8; ++nt) {
            short8 b = *(const short8*)(Wpk + (nt * 16 + lrow) * 64 + qg * 4);
            acc[nt] = __builtin_amdgcn_mfma_f32_16x16x32_bf16(am[kt], b, acc[nt], 0, 0, 0);
        }
    }
    // steps 4-7: A = self, B = W1
#pragma unroll
    for (int kt = 0; kt < 4; ++kt) {
        int qg = kt * 4 + qsel;
#pragma unroll
        for (int nt = 0; nt < 8; ++nt) {
            short8 b = *(const short8*)(Wpk + 8192 + (nt * 16 + lrow) * 64 + qg * 4);
            acc[nt] = __builtin_amdgcn_mfma_f32_16x16x32_bf16(as[kt], b, acc[nt], 0, 0, 0);
        }
    }

    // ---- epilogue ----
    int crow0 = qsel * 4;
    if (!FUSE_FC) {
#pragma unroll
        for (int nt = 0; nt < 8; ++nt) {
            int col = nt * 16 + lrow;
            float bv = bias[col];
#pragma unroll
            for (int r4 = 0; r4 < 4; ++r4) {
                int row = rowBase + crow0 + r4;
                if (row < N_NODES) {
                    float v = acc[nt][r4] + bv;
                    hout[(size_t)row * DIM + col] = f2bf(v > 0.f ? v : 0.f);
                }
            }
        }
    } else {
        float bv[8], wv[8];
#pragma unroll
        for (int nt = 0; nt < 8; ++nt) {
            bv[nt] = bias[nt * 16 + lrow];
            wv[nt] = wfc[nt * 16 + lrow];
        }
        float bf0 = bfc[0];
#pragma unroll
        for (int r4 = 0; r4 < 4; ++r4) {
            float p = 0.f;
#pragma unroll
            for (int nt = 0; nt < 8; ++nt) {
                float v = acc[nt][r4] + bv[nt];
                p += (v > 0.f ? v : 0.f) * wv[nt];
            }
#pragma unroll
            for (int off = 1; off < 16; off <<= 1) p += __shfl_xor(p, off, 64);
            int row = rowBase + crow0 + r4;
            if (lrow == 0 && row < N_NODES) out[row] = p + bf0;
        }
    }
}

// ---- host glue -------------------------------------------------------------

extern "C" void kernel_launch(void* const* d_in, const int* in_sizes, int n_in,
                              void* d_out, int out_size, void* d_ws, size_t ws_size,
                              hipStream_t stream) {
    const float* x  = (const float*)d_in[0];
    const int* edge = (const int*)d_in[1];
    const float* W1l = (const float*)d_in[2];
    const float* b1  = (const float*)d_in[3];
    const float* W1r = (const float*)d_in[4];
    const float* W2l = (const float*)d_in[5];
    const float* b2  = (const float*)d_in[6];
    const float* W2r = (const float*)d_in[7];
    const float* Wfc = (const float*)d_in[8];
    const float* bfc = (const float*)d_in[9];
    float* out = (float*)d_out;  // fp32 output

    char* ws = (char*)d_ws;
    size_t off = 0;
    int* rowptr = (int*)(ws + off); off += ((size_t)N_NODES + 64) * 4;
    int* esrc   = (int*)(ws + off); off += (size_t)N_EDGES * 4;
    int* cur    = (int*)(ws + off); off += (size_t)NB * 4 + 256;
    off = (off + 255) & ~(size_t)255;
    unsigned int* pairs = (unsigned int*)(ws + off); off += (size_t)NB * BKCAP * 4;
    off = (off + 255) & ~(size_t)255;
    unsigned int* wbf = (unsigned int*)(ws + off); off += 4 * 8192 * 4;
    off = (off + 255) & ~(size_t)255;
    unsigned short* xbf  = (unsigned short*)(ws + off); off += (size_t)N_NODES * DIM * 2;
    unsigned short* mean = (unsigned short*)(ws + off); off += (size_t)N_NODES * DIM * 2;
    unsigned short* h1   = (unsigned short*)(ws + off); off += (size_t)N_NODES * DIM * 2;
    // total ~84 MB

    const int gemmBlocks = (N_NODES + 63) / 64;      // 1563 (64 rows/block)
    const int convBlocks = (NXF + WF4 + 255) / 256;  // float4 units

    hipMemsetAsync(cur, 0, NB * sizeof(int), stream);
    binconv_kernel<<<BINB + convBlocks, 256, 0, stream>>>(edge, cur, pairs, x,
                                                          W1l, W1r, W2l, W2r,
                                                          (unsigned int*)xbf, wbf);
    csr_kernel<<<NB, 256, 0, stream>>>(cur, pairs, rowptr, esrc);

    // layer 1: W mats 0,1
    agg_kernel<<<2048, 256, 0, stream>>>((const unsigned int*)xbf, rowptr, esrc,
                                         (unsigned int*)mean);
    gemm_kernel<0><<<gemmBlocks, 256, 0, stream>>>(mean, xbf, wbf, b1, nullptr, nullptr,
                                                   h1, nullptr);
    // layer 2 + fused FC: W mats 2,3
    agg_kernel<<<2048, 256, 0, stream>>>((const unsigned int*)h1, rowptr, esrc,
                                         (unsigned int*)mean);
    gemm_kernel<1><<<gemmBlocks, 256, 0, stream>>>(mean, h1, wbf + 2 * 8192, b2, Wfc, bfc,
                                                   nullptr, out);
}

// Round 6
// 252.663 us; speedup vs baseline: 1.5394x; 1.2764x over previous
//
#include <hip/hip_runtime.h>

#define N_NODES 100000
#define N_EDGES 800000
#define DIM 128

#define NB 391        // buckets of 256 dst nodes
#define BKCAP 2560    // per-bucket window; mean 2046, +11 sigma margin
#define EPB 2048      // edges per bin block
#define BINB ((N_EDGES + EPB - 1) / EPB)  // 391
#define NXF (N_NODES * DIM / 4)           // 3.2M float4 quads in x
#define WF4 (4 * 4096)                    // 4 weight mats, 4096 float4 each

typedef __attribute__((ext_vector_type(8))) short short8;
typedef __attribute__((ext_vector_type(4))) float float4v;
typedef __attribute__((ext_vector_type(2))) float float2v;
typedef __attribute__((ext_vector_type(4))) unsigned int uint4v;
typedef __attribute__((ext_vector_type(2))) unsigned int uint2v;

__device__ __forceinline__ float lo16(unsigned int v) {
    return __uint_as_float(v << 16);
}
__device__ __forceinline__ float hi16(unsigned int v) {
    return __uint_as_float(v & 0xffff0000u);
}
__device__ __forceinline__ float2v unp(unsigned int v) {
    return (float2v){lo16(v), hi16(v)};
}
__device__ __forceinline__ unsigned short f2bf(float f) {
    unsigned int x = __float_as_uint(f);
    unsigned int r = x + 0x7fffu + ((x >> 16) & 1u);  // RNE
    return (unsigned short)(r >> 16);
}
__device__ __forceinline__ unsigned int packbf(float a, float b) {
    return (unsigned int)f2bf(a) | ((unsigned int)f2bf(b) << 16);
}

// wave-inclusive scan over 64 lanes (6 shfl_up, barrier-free)
__device__ __forceinline__ int wave_iscan(int x, int lane) {
#pragma unroll
    for (int off = 1; off < 64; off <<= 1) {
        int n = __shfl_up(x, off, 64);
        x += (lane >= off) ? n : 0;
    }
    return x;
}

// ---- CSR build helpers ------------------------------------------------------

__device__ __forceinline__ void load_edge(const int* __restrict__ edge, int eflag, int e,
                                          int& s, int& d) {
    if (eflag == 0) {  // int64 little-endian: low word holds the value
        s = edge[2 * e];
        d = edge[2 * (N_EDGES + e)];
    } else {
        s = edge[e];
        d = edge[N_EDGES + e];
    }
}

// ---- fused bin + conv -------------------------------------------------------
// Blocks < BINB: bin 2048 edges via LDS histogram -> one global atomic range
// reservation per bucket -> scatter pairs=(src<<8|dst&255) into bucket window.
// Layout detect is per-wave (barrier-free): sample 64 odd dwords of the int64
// view of this block's edge range; any nonzero => int32 layout.
// Blocks >= BINB: fp32 -> packed-bf16 conversion of x then 4 weight matrices.

__global__ __launch_bounds__(256) void binconv_kernel(
    const int* __restrict__ edge, int* __restrict__ cur,
    unsigned int* __restrict__ pairs, const float* __restrict__ x,
    const float* __restrict__ wa, const float* __restrict__ wb,
    const float* __restrict__ wc, const float* __restrict__ wd,
    unsigned int* __restrict__ xdst, unsigned int* __restrict__ wdst) {
    int t = threadIdx.x;
    if (blockIdx.x >= BINB) {  // ---- conv part
        int i = (blockIdx.x - BINB) * 256 + t;  // float4 index
        if (i < NXF) {
            float4 v = ((const float4*)x)[i];
            uint2v o = {packbf(v.x, v.y), packbf(v.z, v.w)};
            *(uint2v*)(xdst + 2 * (size_t)i) = o;
        } else {
            int j = i - NXF;
            if (j < WF4) {
                int m = j >> 12, r = j & 4095;
                const float* src = (m == 0) ? wa : (m == 1) ? wb : (m == 2) ? wc : wd;
                float4 v = ((const float4*)src)[r];
                uint2v o = {packbf(v.x, v.y), packbf(v.z, v.w)};
                *(uint2v*)(wdst + (size_t)m * 8192 + 2 * r) = o;
            }
        }
        return;
    }
    // ---- bin part
    __shared__ int lcnt[NB];
    __shared__ int lbase[NB];
    for (int i = t; i < NB; i += 256) lcnt[i] = 0;
    int e0 = blockIdx.x * EPB;
    // per-wave layout probe (no barrier needed; each wave decides identically)
    int eflag = __any(edge[2 * (e0 + t) + 1] != 0) ? 1 : 0;
    __syncthreads();
    int vb[8];
    unsigned int vp[8];
    bool valid[8];
#pragma unroll
    for (int k = 0; k < 8; ++k) {
        int e = e0 + k * 256 + t;
        valid[k] = false;
        if (e < N_EDGES) {
            int s, d;
            load_edge(edge, eflag, e, s, d);
            if ((unsigned)s < N_NODES && (unsigned)d < N_NODES) {
                valid[k] = true;
                vb[k] = d >> 8;
                vp[k] = ((unsigned int)s << 8) | (unsigned int)(d & 255);
                atomicAdd(&lcnt[vb[k]], 1);
            }
        }
    }
    __syncthreads();
    for (int i = t; i < NB; i += 256) {
        int c = lcnt[i];
        lbase[i] = (c > 0) ? atomicAdd(&cur[i], c) : 0;  // range reservation
        lcnt[i] = 0;  // reuse as local cursor
    }
    __syncthreads();
#pragma unroll
    for (int k = 0; k < 8; ++k) {
        if (valid[k]) {
            int b = vb[k];
            int pos = lbase[b] + atomicAdd(&lcnt[b], 1);
            if (pos < BKCAP)  // statistically unreachable guard
                pairs[(size_t)b * BKCAP + pos] = vp[k];
        }
    }
}

// ---- csr v2: shuffle-scan bucket prefix + per-bucket histogram/scatter ------

__global__ __launch_bounds__(256) void csr_kernel(const int* __restrict__ cur,
                                                  const unsigned int* __restrict__ pairs,
                                                  int* __restrict__ rowptr,
                                                  int* __restrict__ esrc) {
    __shared__ int sh[512];
    __shared__ int hist[256];
    __shared__ int wsum[8];
    int b = blockIdx.x, t = threadIdx.x;
    int lane = t & 63, wv = t >> 6;
    // inclusive scan of 391 bucket totals: 2 elems/thread, wave scan + combine
    int e0 = 2 * t, e1 = 2 * t + 1;
    int v0 = (e0 < NB) ? min(cur[e0], BKCAP) : 0;
    int v1 = (e1 < NB) ? min(cur[e1], BKCAP) : 0;
    int p = wave_iscan(v0 + v1, lane);
    if (lane == 63) wsum[wv] = p;
    hist[t] = 0;  // init for the histogram phase (shares the barrier below)
    __syncthreads();
    int wpre = 0;
#pragma unroll
    for (int w = 0; w < 4; ++w) wpre += (w < wv) ? wsum[w] : 0;
    int incl1 = wpre + p;  // inclusive prefix at elem e1
    sh[e0] = incl1 - v1;   // inclusive at e0
    sh[e1] = incl1;
    __syncthreads();
    int n = min(cur[b], BKCAP);
    int base = sh[b] - n;  // exclusive prefix of bucket b
    if (b == 0 && t == 0) rowptr[N_NODES] = sh[NB - 1];
    // local histogram of dst low-byte
    const unsigned int* pp = pairs + (size_t)b * BKCAP;
    for (int i = t; i < n; i += 256) atomicAdd(&hist[pp[i] & 255u], 1);
    __syncthreads();
    int v = hist[t];
    int ix = wave_iscan(v, lane);
    if (lane == 63) wsum[4 + wv] = ix;
    __syncthreads();
    int wpre2 = 0;
#pragma unroll
    for (int w = 0; w < 4; ++w) wpre2 += (w < wv) ? wsum[4 + w] : 0;
    int excl = wpre2 + ix - v;  // exclusive prefix of hist[t]
    int node = b * 256 + t;
    if (node < N_NODES) rowptr[node] = base + excl;
    hist[t] = excl;  // reuse as per-dst cursors
    __syncthreads();
    for (int i = t; i < n; i += 256) {
        unsigned int pk = pp[i];
        int pos = atomicAdd(&hist[pk & 255u], 1);
        esrc[base + pos] = (int)(pk >> 8);
    }
}

// ---- mean aggregation v9: grid-stride persistent, rowptr software-pipeline --
// 2048 blocks * 4 waves = 32 waves/CU. At 32 waves/CU this runs near the
// random-line service ceiling (R2-R4 decomposition). Do not lower its
// occupancy (R3 lesson: 16 waves/CU -> 1.6 TB/s).

__global__ __launch_bounds__(256) void agg_kernel(const unsigned int* __restrict__ feat2,
                                                  const int* __restrict__ rowptr,
                                                  const int* __restrict__ esrc,
                                                  unsigned int* __restrict__ meanout) {
    int wid = (blockIdx.x * blockDim.x + threadIdx.x) >> 6;  // global wave id
    int lane = threadIdx.x & 63;
    int rowgrp = lane >> 4;
    int dimgrp = lane & 15;
    const int nwaves = 2048 * 4;
    int node = wid;  // wid < 8192 << N_NODES, always valid
    int beg = rowptr[node], end = rowptr[node + 1];
    while (1) {
        int nn = node + nwaves;
        int nbg = 0, nen = 0;
        if (nn < N_NODES) {  // prefetch next node's rowptr pair (overlaps gathers)
            nbg = rowptr[nn];
            nen = rowptr[nn + 1];
        }
        float2v a0 = {0.f, 0.f}, a1 = {0.f, 0.f}, a2 = {0.f, 0.f}, a3 = {0.f, 0.f};
        int e = beg;
        for (; e + 8 <= end; e += 8) {  // 8 edges/iter: 2 dwordx4 in flight
            int s0 = esrc[e + rowgrp];
            int s1 = esrc[e + 4 + rowgrp];
            uint4v v0 = *(const uint4v*)(feat2 + (size_t)s0 * 64 + dimgrp * 4);
            uint4v v1 = *(const uint4v*)(feat2 + (size_t)s1 * 64 + dimgrp * 4);
            a0 += unp(v0.x) + unp(v1.x);
            a1 += unp(v0.y) + unp(v1.y);
            a2 += unp(v0.z) + unp(v1.z);
            a3 += unp(v0.w) + unp(v1.w);
        }
        if (e < end) {  // unified tail: up to 7 edges, 2 parallel masked loads
            int i0 = e + rowgrp, i1 = e + 4 + rowgrp;
            bool ok0 = i0 < end, ok1 = i1 < end;
            int s0 = esrc[ok0 ? i0 : end - 1];
            int s1 = esrc[ok1 ? i1 : end - 1];
            uint4v v0 = *(const uint4v*)(feat2 + (size_t)s0 * 64 + dimgrp * 4);
            uint4v v1 = *(const uint4v*)(feat2 + (size_t)s1 * 64 + dimgrp * 4);
            float m0 = ok0 ? 1.f : 0.f, m1 = ok1 ? 1.f : 0.f;
            float2v m0v = {m0, m0}, m1v = {m1, m1};
            a0 += m0v * unp(v0.x) + m1v * unp(v1.x);
            a1 += m0v * unp(v0.y) + m1v * unp(v1.y);
            a2 += m0v * unp(v0.z) + m1v * unp(v1.z);
            a3 += m0v * unp(v0.w) + m1v * unp(v1.w);
        }
        // reduce-scatter over rowgrp bits: lane keeps accumulator index == rowgrp.
        float2v s0v = (rowgrp & 1) ? a0 : a1;
        float2v k0v = (rowgrp & 1) ? a1 : a0;
        float2v s2v = (rowgrp & 1) ? a2 : a3;
        float2v k2v = (rowgrp & 1) ? a3 : a2;
        k0v.x += __shfl_xor(s0v.x, 16, 64);
        k0v.y += __shfl_xor(s0v.y, 16, 64);
        k2v.x += __shfl_xor(s2v.x, 16, 64);
        k2v.y += __shfl_xor(s2v.y, 16, 64);
        float2v sv = (rowgrp & 2) ? k0v : k2v;
        float2v kv = (rowgrp & 2) ? k2v : k0v;
        kv.x += __shfl_xor(sv.x, 32, 64);
        kv.y += __shfl_xor(sv.y, 32, 64);
        int deg = end - beg;
        float sc = deg > 0 ? 1.f / (float)deg : 0.f;
        meanout[(size_t)node * 64 + dimgrp * 4 + rowgrp] = packbf(kv.x * sc, kv.y * sc);
        if (nn >= N_NODES) break;
        node = nn;
        beg = nbg;
        end = nen;
    }
}

// ---- SAGE GEMM v7: LDS-staged W (v5 addressing) + 16-row wave tile ----------
// R5 post-mortem: v6's per-MFMA GLOBAL B-loads serialize on vmcnt (MfmaUtil
// 2.8%, hbm 0.6 TB/s despite L2-hot W) -> B MUST come from LDS. v7 keeps v5's
// staging/read addressing verbatim (correctness-proven) but:
//   - wave tile 16 rows -> acc[8]=32 VGPR (v6-proven epilogue),
//   - one W matrix staged at a time (32 KB LDS, restage mid-kernel like the
//     R3/R4 fused kernel) -> 4 blocks/CU,
//   - launch_bounds(256,4): 128-VGPR cap, est ~100 used (no spill, R4 lesson)
//     -> 16 waves/CU, 2x v5's 8.
// A-frags (mean+self, 8 independent dwordx4) issued before the staging
// barrier: HBM latency hides under stage+barrier.
// FUSE_FC: epilogue out[row] = sum_col relu(h)[col]*wfc[col] + bfc (fp32).

template <int FUSE_FC>
__global__ __launch_bounds__(256, 4) void gemm_kernel(
    const unsigned short* __restrict__ A0,  // mean rows
    const unsigned short* __restrict__ A1,  // self rows (xbf or h1)
    const unsigned int* __restrict__ Wpk,   // 2 matrices, mat m at dword m*8192
    const float* __restrict__ bias, const float* __restrict__ wfc,
    const float* __restrict__ bfc, unsigned short* __restrict__ hout,
    float* __restrict__ out) {
    __shared__ unsigned int wlds[8192];  // 32 KB: ONE W matrix, frag-major

    int t = threadIdx.x;
    int wave = t >> 6, lane = t & 63;
    int lrow = lane & 15;   // A row-in-tile / B col-in-tile / C col
    int qsel = lane >> 4;   // k-octet select
    int rowBase = blockIdx.x * 64 + wave * 16;

    int rA = rowBase + lrow;
    if (rA >= N_NODES) rA = N_NODES - 1;  // clamp; masked at store

    // all 8 A-frags issued before staging: HBM latency hides under stage+barrier
    short8 am[4], as[4];
#pragma unroll
    for (int kt = 0; kt < 4; ++kt) {
        am[kt] = *(const short8*)(A0 + (size_t)rA * DIM + kt * 32 + qsel * 8);
        as[kt] = *(const short8*)(A1 + (size_t)rA * DIM + kt * 32 + qsel * 8);
    }

    {  // ---- stage W0: thread t -> row (t&127), half (t>>7) -> 8 quads ----
        int row = t & 127, hf = t >> 7;
        const unsigned int* g = Wpk + row * 64 + hf * 32;
#pragma unroll
        for (int q = 0; q < 8; ++q) {
            uint4v v = *(const uint4v*)(g + q * 4);
            *(uint4v*)(wlds + (((hf * 8 + q) * 128 + row) << 2)) = v;
        }
    }
    __syncthreads();

    float4v acc[8];
#pragma unroll
    for (int nt = 0; nt < 8; ++nt) acc[nt] = (float4v){0.f, 0.f, 0.f, 0.f};

    // ---- steps 0-3: A = mean, B = W0 (LDS) ----
#pragma unroll
    for (int kt = 0; kt < 4; ++kt) {
        int qg = kt * 4 + qsel;
#pragma unroll
        for (int nt = 0; nt < 8; ++nt) {
            short8 b = *(const short8*)(wlds + ((qg * 128 + nt * 16 + lrow) << 2));
            acc[nt] = __builtin_amdgcn_mfma_f32_16x16x32_bf16(am[kt], b, acc[nt], 0, 0, 0);
        }
    }

    __syncthreads();
    {  // ---- restage W1 over W0 ----
        int row = t & 127, hf = t >> 7;
        const unsigned int* g = Wpk + 8192 + row * 64 + hf * 32;
#pragma unroll
        for (int q = 0; q < 8; ++q) {
            uint4v v = *(const uint4v*)(g + q * 4);
            *(uint4v*)(wlds + (((hf * 8 + q) * 128 + row) << 2)) = v;
        }
    }
    __syncthreads();

    // ---- steps 4-7: A = self, B = W1 (LDS) ----
#pragma unroll
    for (int kt = 0; kt < 4; ++kt) {
        int qg = kt * 4 + qsel;
#pragma unroll
        for (int nt = 0; nt < 8; ++nt) {
            short8 b = *(const short8*)(wlds + ((qg * 128 + nt * 16 + lrow) << 2));
            acc[nt] = __builtin_amdgcn_mfma_f32_16x16x32_bf16(as[kt], b, acc[nt], 0, 0, 0);
        }
    }

    // ---- epilogue ----
    int crow0 = qsel * 4;
    if (!FUSE_FC) {
#pragma unroll
        for (int nt = 0; nt < 8; ++nt) {
            int col = nt * 16 + lrow;
            float bv = bias[col];
#pragma unroll
            for (int r4 = 0; r4 < 4; ++r4) {
                int row = rowBase + crow0 + r4;
                if (row < N_NODES) {
                    float v = acc[nt][r4] + bv;
                    hout[(size_t)row * DIM + col] = f2bf(v > 0.f ? v : 0.f);
                }
            }
        }
    } else {
        float bv[8], wv[8];
#pragma unroll
        for (int nt = 0; nt < 8; ++nt) {
            bv[nt] = bias[nt * 16 + lrow];
            wv[nt] = wfc[nt * 16 + lrow];
        }
        float bf0 = bfc[0];
#pragma unroll
        for (int r4 = 0; r4 < 4; ++r4) {
            float p = 0.f;
#pragma unroll
            for (int nt = 0; nt < 8; ++nt) {
                float v = acc[nt][r4] + bv[nt];
                p += (v > 0.f ? v : 0.f) * wv[nt];
            }
#pragma unroll
            for (int off = 1; off < 16; off <<= 1) p += __shfl_xor(p, off, 64);
            int row = rowBase + crow0 + r4;
            if (lrow == 0 && row < N_NODES) out[row] = p + bf0;
        }
    }
}

// ---- host glue -------------------------------------------------------------

extern "C" void kernel_launch(void* const* d_in, const int* in_sizes, int n_in,
                              void* d_out, int out_size, void* d_ws, size_t ws_size,
                              hipStream_t stream) {
    const float* x  = (const float*)d_in[0];
    const int* edge = (const int*)d_in[1];
    const float* W1l = (const float*)d_in[2];
    const float* b1  = (const float*)d_in[3];
    const float* W1r = (const float*)d_in[4];
    const float* W2l = (const float*)d_in[5];
    const float* b2  = (const float*)d_in[6];
    const float* W2r = (const float*)d_in[7];
    const float* Wfc = (const float*)d_in[8];
    const float* bfc = (const float*)d_in[9];
    float* out = (float*)d_out;  // fp32 output

    char* ws = (char*)d_ws;
    size_t off = 0;
    int* rowptr = (int*)(ws + off); off += ((size_t)N_NODES + 64) * 4;
    int* esrc   = (int*)(ws + off); off += (size_t)N_EDGES * 4;
    int* cur    = (int*)(ws + off); off += (size_t)NB * 4 + 256;
    off = (off + 255) & ~(size_t)255;
    unsigned int* pairs = (unsigned int*)(ws + off); off += (size_t)NB * BKCAP * 4;
    off = (off + 255) & ~(size_t)255;
    unsigned int* wbf = (unsigned int*)(ws + off); off += 4 * 8192 * 4;
    off = (off + 255) & ~(size_t)255;
    unsigned short* xbf  = (unsigned short*)(ws + off); off += (size_t)N_NODES * DIM * 2;
    unsigned short* mean = (unsigned short*)(ws + off); off += (size_t)N_NODES * DIM * 2;
    unsigned short* h1   = (unsigned short*)(ws + off); off += (size_t)N_NODES * DIM * 2;
    // total ~84 MB

    const int gemmBlocks = (N_NODES + 63) / 64;      // 1563 (64 rows/block)
    const int convBlocks = (NXF + WF4 + 255) / 256;  // float4 units

    hipMemsetAsync(cur, 0, NB * sizeof(int), stream);
    binconv_kernel<<<BINB + convBlocks, 256, 0, stream>>>(edge, cur, pairs, x,
                                                          W1l, W1r, W2l, W2r,
                                                          (unsigned int*)xbf, wbf);
    csr_kernel<<<NB, 256, 0, stream>>>(cur, pairs, rowptr, esrc);

    // layer 1: W mats 0,1
    agg_kernel<<<2048, 256, 0, stream>>>((const unsigned int*)xbf, rowptr, esrc,
                                         (unsigned int*)mean);
    gemm_kernel<0><<<gemmBlocks, 256, 0, stream>>>(mean, xbf, wbf, b1, nullptr, nullptr,
                                                   h1, nullptr);
    // layer 2 + fused FC: W mats 2,3
    agg_kernel<<<2048, 256, 0, stream>>>((const unsigned int*)h1, rowptr, esrc,
                                         (unsigned int*)mean);
    gemm_kernel<1><<<gemmBlocks, 256, 0, stream>>>(mean, h1, wbf + 2 * 8192, b2, Wfc, bfc,
                                                   nullptr, out);
}

// Round 7
// 244.529 us; speedup vs baseline: 1.5906x; 1.0333x over previous
//
#include <hip/hip_runtime.h>

#define N_NODES 100000
#define N_EDGES 800000
#define DIM 128

#define NB 391        // buckets of 256 dst nodes
#define BKCAP 2560    // per-bucket window; mean 2046, +11 sigma margin
#define EPB 2048      // edges per bin block
#define BINB ((N_EDGES + EPB - 1) / EPB)  // 391
#define NXF (N_NODES * DIM / 4)           // 3.2M float4 quads in x
#define WF4 (4 * 4096)                    // 4 weight mats, 4096 float4 each

typedef __attribute__((ext_vector_type(8))) short short8;
typedef __attribute__((ext_vector_type(4))) float float4v;
typedef __attribute__((ext_vector_type(2))) float float2v;
typedef __attribute__((ext_vector_type(4))) unsigned int uint4v;
typedef __attribute__((ext_vector_type(2))) unsigned int uint2v;

__device__ __forceinline__ float lo16(unsigned int v) {
    return __uint_as_float(v << 16);
}
__device__ __forceinline__ float hi16(unsigned int v) {
    return __uint_as_float(v & 0xffff0000u);
}
__device__ __forceinline__ float2v unp(unsigned int v) {
    return (float2v){lo16(v), hi16(v)};
}
__device__ __forceinline__ unsigned short f2bf(float f) {
    unsigned int x = __float_as_uint(f);
    unsigned int r = x + 0x7fffu + ((x >> 16) & 1u);  // RNE
    return (unsigned short)(r >> 16);
}
__device__ __forceinline__ unsigned int packbf(float a, float b) {
    return (unsigned int)f2bf(a) | ((unsigned int)f2bf(b) << 16);
}

// wave-inclusive scan over 64 lanes (6 shfl_up, barrier-free)
__device__ __forceinline__ int wave_iscan(int x, int lane) {
#pragma unroll
    for (int off = 1; off < 64; off <<= 1) {
        int n = __shfl_up(x, off, 64);
        x += (lane >= off) ? n : 0;
    }
    return x;
}

// ---- CSR build helpers ------------------------------------------------------

__device__ __forceinline__ void load_edge(const int* __restrict__ edge, int eflag, int e,
                                          int& s, int& d) {
    if (eflag == 0) {  // int64 little-endian: low word holds the value
        s = edge[2 * e];
        d = edge[2 * (N_EDGES + e)];
    } else {
        s = edge[e];
        d = edge[N_EDGES + e];
    }
}

// ---- fused bin + conv -------------------------------------------------------
// Blocks < BINB: bin 2048 edges via LDS histogram -> one global atomic range
// reservation per bucket -> scatter pairs=(src<<8|dst&255) into bucket window.
// Layout detect is per-wave (barrier-free): sample 64 odd dwords of the int64
// view of this block's edge range; any nonzero => int32 layout.
// Blocks >= BINB: fp32 -> packed-bf16 conversion of x then 4 weight matrices.

__global__ __launch_bounds__(256) void binconv_kernel(
    const int* __restrict__ edge, int* __restrict__ cur,
    unsigned int* __restrict__ pairs, const float* __restrict__ x,
    const float* __restrict__ wa, const float* __restrict__ wb,
    const float* __restrict__ wc, const float* __restrict__ wd,
    unsigned int* __restrict__ xdst, unsigned int* __restrict__ wdst) {
    int t = threadIdx.x;
    if (blockIdx.x >= BINB) {  // ---- conv part
        int i = (blockIdx.x - BINB) * 256 + t;  // float4 index
        if (i < NXF) {
            float4 v = ((const float4*)x)[i];
            uint2v o = {packbf(v.x, v.y), packbf(v.z, v.w)};
            *(uint2v*)(xdst + 2 * (size_t)i) = o;
        } else {
            int j = i - NXF;
            if (j < WF4) {
                int m = j >> 12, r = j & 4095;
                const float* src = (m == 0) ? wa : (m == 1) ? wb : (m == 2) ? wc : wd;
                float4 v = ((const float4*)src)[r];
                uint2v o = {packbf(v.x, v.y), packbf(v.z, v.w)};
                *(uint2v*)(wdst + (size_t)m * 8192 + 2 * r) = o;
            }
        }
        return;
    }
    // ---- bin part
    __shared__ int lcnt[NB];
    __shared__ int lbase[NB];
    for (int i = t; i < NB; i += 256) lcnt[i] = 0;
    int e0 = blockIdx.x * EPB;
    // per-wave layout probe (no barrier needed; each wave decides identically)
    int eflag = __any(edge[2 * (e0 + t) + 1] != 0) ? 1 : 0;
    __syncthreads();
    int vb[8];
    unsigned int vp[8];
    bool valid[8];
#pragma unroll
    for (int k = 0; k < 8; ++k) {
        int e = e0 + k * 256 + t;
        valid[k] = false;
        if (e < N_EDGES) {
            int s, d;
            load_edge(edge, eflag, e, s, d);
            if ((unsigned)s < N_NODES && (unsigned)d < N_NODES) {
                valid[k] = true;
                vb[k] = d >> 8;
                vp[k] = ((unsigned int)s << 8) | (unsigned int)(d & 255);
                atomicAdd(&lcnt[vb[k]], 1);
            }
        }
    }
    __syncthreads();
    for (int i = t; i < NB; i += 256) {
        int c = lcnt[i];
        lbase[i] = (c > 0) ? atomicAdd(&cur[i], c) : 0;  // range reservation
        lcnt[i] = 0;  // reuse as local cursor
    }
    __syncthreads();
#pragma unroll
    for (int k = 0; k < 8; ++k) {
        if (valid[k]) {
            int b = vb[k];
            int pos = lbase[b] + atomicAdd(&lcnt[b], 1);
            if (pos < BKCAP)  // statistically unreachable guard
                pairs[(size_t)b * BKCAP + pos] = vp[k];
        }
    }
}

// ---- csr v2: shuffle-scan bucket prefix + per-bucket histogram/scatter ------

__global__ __launch_bounds__(256) void csr_kernel(const int* __restrict__ cur,
                                                  const unsigned int* __restrict__ pairs,
                                                  int* __restrict__ rowptr,
                                                  int* __restrict__ esrc) {
    __shared__ int sh[512];
    __shared__ int hist[256];
    __shared__ int wsum[8];
    int b = blockIdx.x, t = threadIdx.x;
    int lane = t & 63, wv = t >> 6;
    // inclusive scan of 391 bucket totals: 2 elems/thread, wave scan + combine
    int e0 = 2 * t, e1 = 2 * t + 1;
    int v0 = (e0 < NB) ? min(cur[e0], BKCAP) : 0;
    int v1 = (e1 < NB) ? min(cur[e1], BKCAP) : 0;
    int p = wave_iscan(v0 + v1, lane);
    if (lane == 63) wsum[wv] = p;
    hist[t] = 0;  // init for the histogram phase (shares the barrier below)
    __syncthreads();
    int wpre = 0;
#pragma unroll
    for (int w = 0; w < 4; ++w) wpre += (w < wv) ? wsum[w] : 0;
    int incl1 = wpre + p;  // inclusive prefix at elem e1
    sh[e0] = incl1 - v1;   // inclusive at e0
    sh[e1] = incl1;
    __syncthreads();
    int n = min(cur[b], BKCAP);
    int base = sh[b] - n;  // exclusive prefix of bucket b
    if (b == 0 && t == 0) rowptr[N_NODES] = sh[NB - 1];
    // local histogram of dst low-byte
    const unsigned int* pp = pairs + (size_t)b * BKCAP;
    for (int i = t; i < n; i += 256) atomicAdd(&hist[pp[i] & 255u], 1);
    __syncthreads();
    int v = hist[t];
    int ix = wave_iscan(v, lane);
    if (lane == 63) wsum[4 + wv] = ix;
    __syncthreads();
    int wpre2 = 0;
#pragma unroll
    for (int w = 0; w < 4; ++w) wpre2 += (w < wv) ? wsum[4 + w] : 0;
    int excl = wpre2 + ix - v;  // exclusive prefix of hist[t]
    int node = b * 256 + t;
    if (node < N_NODES) rowptr[node] = base + excl;
    hist[t] = excl;  // reuse as per-dst cursors
    __syncthreads();
    for (int i = t; i < n; i += 256) {
        unsigned int pk = pp[i];
        int pos = atomicAdd(&hist[pk & 255u], 1);
        esrc[base + pos] = (int)(pk >> 8);
    }
}

// ---- mean aggregation v9: grid-stride persistent, rowptr software-pipeline --
// 2048 blocks * 4 waves = 32 waves/CU. Measured ~22 us/layer (~10.6 TB/s
// effective gather service = L3-served, near ceiling). Do not lower its
// occupancy (R3 lesson: 16 waves/CU -> 1.6 TB/s).

__global__ __launch_bounds__(256) void agg_kernel(const unsigned int* __restrict__ feat2,
                                                  const int* __restrict__ rowptr,
                                                  const int* __restrict__ esrc,
                                                  unsigned int* __restrict__ meanout) {
    int wid = (blockIdx.x * blockDim.x + threadIdx.x) >> 6;  // global wave id
    int lane = threadIdx.x & 63;
    int rowgrp = lane >> 4;
    int dimgrp = lane & 15;
    const int nwaves = 2048 * 4;
    int node = wid;  // wid < 8192 << N_NODES, always valid
    int beg = rowptr[node], end = rowptr[node + 1];
    while (1) {
        int nn = node + nwaves;
        int nbg = 0, nen = 0;
        if (nn < N_NODES) {  // prefetch next node's rowptr pair (overlaps gathers)
            nbg = rowptr[nn];
            nen = rowptr[nn + 1];
        }
        float2v a0 = {0.f, 0.f}, a1 = {0.f, 0.f}, a2 = {0.f, 0.f}, a3 = {0.f, 0.f};
        int e = beg;
        for (; e + 8 <= end; e += 8) {  // 8 edges/iter: 2 dwordx4 in flight
            int s0 = esrc[e + rowgrp];
            int s1 = esrc[e + 4 + rowgrp];
            uint4v v0 = *(const uint4v*)(feat2 + (size_t)s0 * 64 + dimgrp * 4);
            uint4v v1 = *(const uint4v*)(feat2 + (size_t)s1 * 64 + dimgrp * 4);
            a0 += unp(v0.x) + unp(v1.x);
            a1 += unp(v0.y) + unp(v1.y);
            a2 += unp(v0.z) + unp(v1.z);
            a3 += unp(v0.w) + unp(v1.w);
        }
        if (e < end) {  // unified tail: up to 7 edges, 2 parallel masked loads
            int i0 = e + rowgrp, i1 = e + 4 + rowgrp;
            bool ok0 = i0 < end, ok1 = i1 < end;
            int s0 = esrc[ok0 ? i0 : end - 1];
            int s1 = esrc[ok1 ? i1 : end - 1];
            uint4v v0 = *(const uint4v*)(feat2 + (size_t)s0 * 64 + dimgrp * 4);
            uint4v v1 = *(const uint4v*)(feat2 + (size_t)s1 * 64 + dimgrp * 4);
            float m0 = ok0 ? 1.f : 0.f, m1 = ok1 ? 1.f : 0.f;
            float2v m0v = {m0, m0}, m1v = {m1, m1};
            a0 += m0v * unp(v0.x) + m1v * unp(v1.x);
            a1 += m0v * unp(v0.y) + m1v * unp(v1.y);
            a2 += m0v * unp(v0.z) + m1v * unp(v1.z);
            a3 += m0v * unp(v0.w) + m1v * unp(v1.w);
        }
        // reduce-scatter over rowgrp bits: lane keeps accumulator index == rowgrp.
        float2v s0v = (rowgrp & 1) ? a0 : a1;
        float2v k0v = (rowgrp & 1) ? a1 : a0;
        float2v s2v = (rowgrp & 1) ? a2 : a3;
        float2v k2v = (rowgrp & 1) ? a3 : a2;
        k0v.x += __shfl_xor(s0v.x, 16, 64);
        k0v.y += __shfl_xor(s0v.y, 16, 64);
        k2v.x += __shfl_xor(s2v.x, 16, 64);
        k2v.y += __shfl_xor(s2v.y, 16, 64);
        float2v sv = (rowgrp & 2) ? k0v : k2v;
        float2v kv = (rowgrp & 2) ? k2v : k0v;
        kv.x += __shfl_xor(sv.x, 32, 64);
        kv.y += __shfl_xor(sv.y, 32, 64);
        int deg = end - beg;
        float sc = deg > 0 ? 1.f / (float)deg : 0.f;
        meanout[(size_t)node * 64 + dimgrp * 4 + rowgrp] = packbf(kv.x * sc, kv.y * sc);
        if (nn >= N_NODES) break;
        node = nn;
        beg = nbg;
        end = nen;
    }
}

// ---- SAGE GEMM v8: both-mats-once LDS + 16-row tiles + full grid ------------
// Cross-round algebra: v5 (1 stage, 391 blocks @1.53/CU) = 43.6 us; v7
// (restage, 16 w/CU) = 50.1; R3's fused gemm phase (same math) ~15-20 us.
// v8 = intersection of proven-good pieces:
//   - 512-thread blocks, 8 waves x 16-row tiles = 128 rows/block, grid 782
//     -> full residency at 2 blocks/CU, 1.53 block-passes;
//   - BOTH W mats staged once (64 KB LDS, v5 frag-major addressing verbatim),
//     ONE barrier, no mid-kernel restage (v7 regression);
//   - A-frags (8 independent dwordx4) issued before the barrier (T14);
//   - acc[8]=32 VGPR epilogue (v6/v7-proven);
//   - launch_bounds(512,4): 2 blocks/CU = 16 waves/CU, 128-VGPR cap (no
//     spill: v7 measured 44 VGPR in this shape; R4 lesson respected).
// FUSE_FC: epilogue out[row] = sum_col relu(h)[col]*wfc[col] + bfc (fp32).

template <int FUSE_FC>
__global__ __launch_bounds__(512, 4) void gemm_kernel(
    const unsigned short* __restrict__ A0,  // mean rows
    const unsigned short* __restrict__ A1,  // self rows (xbf or h1)
    const unsigned int* __restrict__ Wpk,   // 2 matrices, mat m at dword m*8192
    const float* __restrict__ bias, const float* __restrict__ wfc,
    const float* __restrict__ bfc, unsigned short* __restrict__ hout,
    float* __restrict__ out) {
    __shared__ unsigned int wlds[16384];  // 64 KB: BOTH W matrices, frag-major

    int t = threadIdx.x;
    int wave = t >> 6, lane = t & 63;
    int lrow = lane & 15;   // A row-in-tile / B col-in-tile / C col
    int qsel = lane >> 4;   // k-octet select
    int rowBase = blockIdx.x * 128 + wave * 16;

    int rA = rowBase + lrow;
    if (rA >= N_NODES) rA = N_NODES - 1;  // clamp; masked at store

    // all 8 A-frags issued before staging: HBM latency hides under stage+barrier
    short8 am[4], as[4];
#pragma unroll
    for (int kt = 0; kt < 4; ++kt) {
        am[kt] = *(const short8*)(A0 + (size_t)rA * DIM + kt * 32 + qsel * 8);
        as[kt] = *(const short8*)(A1 + (size_t)rA * DIM + kt * 32 + qsel * 8);
    }

    {  // ---- stage BOTH mats: thread t -> mat (t>>8), row (tid&127), half ----
        int m = t >> 8, tid = t & 255;
        int row = tid & 127, hf = tid >> 7;
        const unsigned int* g = Wpk + m * 8192 + row * 64 + hf * 32;
        unsigned int* l = wlds + m * 8192;
#pragma unroll
        for (int q = 0; q < 8; ++q) {
            uint4v v = *(const uint4v*)(g + q * 4);
            *(uint4v*)(l + (((hf * 8 + q) * 128 + row) << 2)) = v;
        }
    }
    __syncthreads();

    float4v acc[8];
#pragma unroll
    for (int nt = 0; nt < 8; ++nt) acc[nt] = (float4v){0.f, 0.f, 0.f, 0.f};

    // ---- steps 0-3: A = mean, B = W0 (LDS) ----
#pragma unroll
    for (int kt = 0; kt < 4; ++kt) {
        int qg = kt * 4 + qsel;
#pragma unroll
        for (int nt = 0; nt < 8; ++nt) {
            short8 b = *(const short8*)(wlds + ((qg * 128 + nt * 16 + lrow) << 2));
            acc[nt] = __builtin_amdgcn_mfma_f32_16x16x32_bf16(am[kt], b, acc[nt], 0, 0, 0);
        }
    }
    // ---- steps 4-7: A = self, B = W1 (LDS, second half) ----
#pragma unroll
    for (int kt = 0; kt < 4; ++kt) {
        int qg = kt * 4 + qsel;
#pragma unroll
        for (int nt = 0; nt < 8; ++nt) {
            short8 b = *(const short8*)(wlds + 8192 + ((qg * 128 + nt * 16 + lrow) << 2));
            acc[nt] = __builtin_amdgcn_mfma_f32_16x16x32_bf16(as[kt], b, acc[nt], 0, 0, 0);
        }
    }

    // ---- epilogue ----
    int crow0 = qsel * 4;
    if (!FUSE_FC) {
#pragma unroll
        for (int nt = 0; nt < 8; ++nt) {
            int col = nt * 16 + lrow;
            float bv = bias[col];
#pragma unroll
            for (int r4 = 0; r4 < 4; ++r4) {
                int row = rowBase + crow0 + r4;
                if (row < N_NODES) {
                    float v = acc[nt][r4] + bv;
                    hout[(size_t)row * DIM + col] = f2bf(v > 0.f ? v : 0.f);
                }
            }
        }
    } else {
        float bv[8], wv[8];
#pragma unroll
        for (int nt = 0; nt < 8; ++nt) {
            bv[nt] = bias[nt * 16 + lrow];
            wv[nt] = wfc[nt * 16 + lrow];
        }
        float bf0 = bfc[0];
#pragma unroll
        for (int r4 = 0; r4 < 4; ++r4) {
            float p = 0.f;
#pragma unroll
            for (int nt = 0; nt < 8; ++nt) {
                float v = acc[nt][r4] + bv[nt];
                p += (v > 0.f ? v : 0.f) * wv[nt];
            }
#pragma unroll
            for (int off = 1; off < 16; off <<= 1) p += __shfl_xor(p, off, 64);
            int row = rowBase + crow0 + r4;
            if (lrow == 0 && row < N_NODES) out[row] = p + bf0;
        }
    }
}

// ---- host glue -------------------------------------------------------------

extern "C" void kernel_launch(void* const* d_in, const int* in_sizes, int n_in,
                              void* d_out, int out_size, void* d_ws, size_t ws_size,
                              hipStream_t stream) {
    const float* x  = (const float*)d_in[0];
    const int* edge = (const int*)d_in[1];
    const float* W1l = (const float*)d_in[2];
    const float* b1  = (const float*)d_in[3];
    const float* W1r = (const float*)d_in[4];
    const float* W2l = (const float*)d_in[5];
    const float* b2  = (const float*)d_in[6];
    const float* W2r = (const float*)d_in[7];
    const float* Wfc = (const float*)d_in[8];
    const float* bfc = (const float*)d_in[9];
    float* out = (float*)d_out;  // fp32 output

    char* ws = (char*)d_ws;
    size_t off = 0;
    int* rowptr = (int*)(ws + off); off += ((size_t)N_NODES + 64) * 4;
    int* esrc   = (int*)(ws + off); off += (size_t)N_EDGES * 4;
    int* cur    = (int*)(ws + off); off += (size_t)NB * 4 + 256;
    off = (off + 255) & ~(size_t)255;
    unsigned int* pairs = (unsigned int*)(ws + off); off += (size_t)NB * BKCAP * 4;
    off = (off + 255) & ~(size_t)255;
    unsigned int* wbf = (unsigned int*)(ws + off); off += 4 * 8192 * 4;
    off = (off + 255) & ~(size_t)255;
    unsigned short* xbf  = (unsigned short*)(ws + off); off += (size_t)N_NODES * DIM * 2;
    unsigned short* mean = (unsigned short*)(ws + off); off += (size_t)N_NODES * DIM * 2;
    unsigned short* h1   = (unsigned short*)(ws + off); off += (size_t)N_NODES * DIM * 2;
    // total ~84 MB

    const int gemmBlocks = (N_NODES + 127) / 128;    // 782 (128 rows/block)
    const int convBlocks = (NXF + WF4 + 255) / 256;  // float4 units

    hipMemsetAsync(cur, 0, NB * sizeof(int), stream);
    binconv_kernel<<<BINB + convBlocks, 256, 0, stream>>>(edge, cur, pairs, x,
                                                          W1l, W1r, W2l, W2r,
                                                          (unsigned int*)xbf, wbf);
    csr_kernel<<<NB, 256, 0, stream>>>(cur, pairs, rowptr, esrc);

    // layer 1: W mats 0,1
    agg_kernel<<<2048, 256, 0, stream>>>((const unsigned int*)xbf, rowptr, esrc,
                                         (unsigned int*)mean);
    gemm_kernel<0><<<gemmBlocks, 512, 0, stream>>>(mean, xbf, wbf, b1, nullptr, nullptr,
                                                   h1, nullptr);
    // layer 2 + fused FC: W mats 2,3
    agg_kernel<<<2048, 256, 0, stream>>>((const unsigned int*)h1, rowptr, esrc,
                                         (unsigned int*)mean);
    gemm_kernel<1><<<gemmBlocks, 512, 0, stream>>>(mean, h1, wbf + 2 * 8192, b2, Wfc, bfc,
                                                   nullptr, out);
}

// Round 9
// 240.309 us; speedup vs baseline: 1.6185x; 1.0176x over previous
//
#include <hip/hip_runtime.h>

#define N_NODES 100000
#define N_EDGES 800000
#define DIM 128

#define NB 391        // buckets of 256 dst nodes
#define BKCAP 2560    // per-bucket window; mean 2046, +11 sigma margin
#define EPB 2048      // edges per bin block
#define BINB ((N_EDGES + EPB - 1) / EPB)  // 391
#define NXF (N_NODES * DIM / 4)           // 3.2M float4 quads in x
#define WF4 (4 * 4096)                    // 4 weight mats, 4096 float4 each

typedef __attribute__((ext_vector_type(8))) short short8;
typedef __attribute__((ext_vector_type(4))) float float4v;
typedef __attribute__((ext_vector_type(2))) float float2v;
typedef __attribute__((ext_vector_type(4))) unsigned int uint4v;
typedef __attribute__((ext_vector_type(2))) unsigned int uint2v;

__device__ __forceinline__ float lo16(unsigned int v) {
    return __uint_as_float(v << 16);
}
__device__ __forceinline__ float hi16(unsigned int v) {
    return __uint_as_float(v & 0xffff0000u);
}
__device__ __forceinline__ float2v unp(unsigned int v) {
    return (float2v){lo16(v), hi16(v)};
}
__device__ __forceinline__ unsigned short f2bf(float f) {
    unsigned int x = __float_as_uint(f);
    unsigned int r = x + 0x7fffu + ((x >> 16) & 1u);  // RNE
    return (unsigned short)(r >> 16);
}
__device__ __forceinline__ unsigned int packbf(float a, float b) {
    return (unsigned int)f2bf(a) | ((unsigned int)f2bf(b) << 16);
}

// wave-inclusive scan over 64 lanes (6 shfl_up, barrier-free)
__device__ __forceinline__ int wave_iscan(int x, int lane) {
#pragma unroll
    for (int off = 1; off < 64; off <<= 1) {
        int n = __shfl_up(x, off, 64);
        x += (lane >= off) ? n : 0;
    }
    return x;
}

// ---- CSR build helpers ------------------------------------------------------

__device__ __forceinline__ void load_edge(const int* __restrict__ edge, int eflag, int e,
                                          int& s, int& d) {
    if (eflag == 0) {  // int64 little-endian: low word holds the value
        s = edge[2 * e];
        d = edge[2 * (N_EDGES + e)];
    } else {
        s = edge[e];
        d = edge[N_EDGES + e];
    }
}

// ---- fused bin + conv -------------------------------------------------------
// Blocks < BINB: bin 2048 edges via LDS histogram -> one global atomic range
// reservation per bucket -> scatter pairs=(src<<8|dst&255) into bucket window.
// Layout detect is per-wave (barrier-free): sample 64 odd dwords of the int64
// view of this block's edge range; any nonzero => int32 layout.
// Blocks >= BINB: fp32 -> packed-bf16 conversion of x then 4 weight matrices.

__global__ __launch_bounds__(256) void binconv_kernel(
    const int* __restrict__ edge, int* __restrict__ cur,
    unsigned int* __restrict__ pairs, const float* __restrict__ x,
    const float* __restrict__ wa, const float* __restrict__ wb,
    const float* __restrict__ wc, const float* __restrict__ wd,
    unsigned int* __restrict__ xdst, unsigned int* __restrict__ wdst) {
    int t = threadIdx.x;
    if (blockIdx.x >= BINB) {  // ---- conv part
        int i = (blockIdx.x - BINB) * 256 + t;  // float4 index
        if (i < NXF) {
            float4 v = ((const float4*)x)[i];
            uint2v o = {packbf(v.x, v.y), packbf(v.z, v.w)};
            *(uint2v*)(xdst + 2 * (size_t)i) = o;
        } else {
            int j = i - NXF;
            if (j < WF4) {
                int m = j >> 12, r = j & 4095;
                const float* src = (m == 0) ? wa : (m == 1) ? wb : (m == 2) ? wc : wd;
                float4 v = ((const float4*)src)[r];
                uint2v o = {packbf(v.x, v.y), packbf(v.z, v.w)};
                *(uint2v*)(wdst + (size_t)m * 8192 + 2 * r) = o;
            }
        }
        return;
    }
    // ---- bin part
    __shared__ int lcnt[NB];
    __shared__ int lbase[NB];
    for (int i = t; i < NB; i += 256) lcnt[i] = 0;
    int e0 = blockIdx.x * EPB;
    // per-wave layout probe (no barrier needed; each wave decides identically)
    int eflag = __any(edge[2 * (e0 + t) + 1] != 0) ? 1 : 0;
    __syncthreads();
    int vb[8];
    unsigned int vp[8];
    bool valid[8];
#pragma unroll
    for (int k = 0; k < 8; ++k) {
        int e = e0 + k * 256 + t;
        valid[k] = false;
        if (e < N_EDGES) {
            int s, d;
            load_edge(edge, eflag, e, s, d);
            if ((unsigned)s < N_NODES && (unsigned)d < N_NODES) {
                valid[k] = true;
                vb[k] = d >> 8;
                vp[k] = ((unsigned int)s << 8) | (unsigned int)(d & 255);
                atomicAdd(&lcnt[vb[k]], 1);
            }
        }
    }
    __syncthreads();
    for (int i = t; i < NB; i += 256) {
        int c = lcnt[i];
        lbase[i] = (c > 0) ? atomicAdd(&cur[i], c) : 0;  // range reservation
        lcnt[i] = 0;  // reuse as local cursor
    }
    __syncthreads();
#pragma unroll
    for (int k = 0; k < 8; ++k) {
        if (valid[k]) {
            int b = vb[k];
            int pos = lbase[b] + atomicAdd(&lcnt[b], 1);
            if (pos < BKCAP)  // statistically unreachable guard
                pairs[(size_t)b * BKCAP + pos] = vp[k];
        }
    }
}

// ---- csr v2: shuffle-scan bucket prefix + per-bucket histogram/scatter ------

__global__ __launch_bounds__(256) void csr_kernel(const int* __restrict__ cur,
                                                  const unsigned int* __restrict__ pairs,
                                                  int* __restrict__ rowptr,
                                                  int* __restrict__ esrc) {
    __shared__ int sh[512];
    __shared__ int hist[256];
    __shared__ int wsum[8];
    int b = blockIdx.x, t = threadIdx.x;
    int lane = t & 63, wv = t >> 6;
    // inclusive scan of 391 bucket totals: 2 elems/thread, wave scan + combine
    int e0 = 2 * t, e1 = 2 * t + 1;
    int v0 = (e0 < NB) ? min(cur[e0], BKCAP) : 0;
    int v1 = (e1 < NB) ? min(cur[e1], BKCAP) : 0;
    int p = wave_iscan(v0 + v1, lane);
    if (lane == 63) wsum[wv] = p;
    hist[t] = 0;  // init for the histogram phase (shares the barrier below)
    __syncthreads();
    int wpre = 0;
#pragma unroll
    for (int w = 0; w < 4; ++w) wpre += (w < wv) ? wsum[w] : 0;
    int incl1 = wpre + p;  // inclusive prefix at elem e1
    sh[e0] = incl1 - v1;   // inclusive at e0
    sh[e1] = incl1;
    __syncthreads();
    int n = min(cur[b], BKCAP);
    int base = sh[b] - n;  // exclusive prefix of bucket b
    if (b == 0 && t == 0) rowptr[N_NODES] = sh[NB - 1];
    // local histogram of dst low-byte
    const unsigned int* pp = pairs + (size_t)b * BKCAP;
    for (int i = t; i < n; i += 256) atomicAdd(&hist[pp[i] & 255u], 1);
    __syncthreads();
    int v = hist[t];
    int ix = wave_iscan(v, lane);
    if (lane == 63) wsum[4 + wv] = ix;
    __syncthreads();
    int wpre2 = 0;
#pragma unroll
    for (int w = 0; w < 4; ++w) wpre2 += (w < wv) ? wsum[4 + w] : 0;
    int excl = wpre2 + ix - v;  // exclusive prefix of hist[t]
    int node = b * 256 + t;
    if (node < N_NODES) rowptr[node] = base + excl;
    hist[t] = excl;  // reuse as per-dst cursors
    __syncthreads();
    for (int i = t; i < n; i += 256) {
        unsigned int pk = pp[i];
        int pos = atomicAdd(&hist[pk & 255u], 1);
        esrc[base + pos] = (int)(pk >> 8);
    }
}

// ---- mean aggregation v9: grid-stride persistent, rowptr software-pipeline --
// 2048 blocks * 4 waves = 32 waves/CU. L2-miss-bound (R3 counters: BW scales
// with occupancy; 16 w/CU -> 1.6 TB/s). Keep at 32 waves/CU.

__global__ __launch_bounds__(256) void agg_kernel(const unsigned int* __restrict__ feat2,
                                                  const int* __restrict__ rowptr,
                                                  const int* __restrict__ esrc,
                                                  unsigned int* __restrict__ meanout) {
    int wid = (blockIdx.x * blockDim.x + threadIdx.x) >> 6;  // global wave id
    int lane = threadIdx.x & 63;
    int rowgrp = lane >> 4;
    int dimgrp = lane & 15;
    const int nwaves = 2048 * 4;
    int node = wid;  // wid < 8192 << N_NODES, always valid
    int beg = rowptr[node], end = rowptr[node + 1];
    while (1) {
        int nn = node + nwaves;
        int nbg = 0, nen = 0;
        if (nn < N_NODES) {  // prefetch next node's rowptr pair (overlaps gathers)
            nbg = rowptr[nn];
            nen = rowptr[nn + 1];
        }
        float2v a0 = {0.f, 0.f}, a1 = {0.f, 0.f}, a2 = {0.f, 0.f}, a3 = {0.f, 0.f};
        int e = beg;
        for (; e + 8 <= end; e += 8) {  // 8 edges/iter: 2 dwordx4 in flight
            int s0 = esrc[e + rowgrp];
            int s1 = esrc[e + 4 + rowgrp];
            uint4v v0 = *(const uint4v*)(feat2 + (size_t)s0 * 64 + dimgrp * 4);
            uint4v v1 = *(const uint4v*)(feat2 + (size_t)s1 * 64 + dimgrp * 4);
            a0 += unp(v0.x) + unp(v1.x);
            a1 += unp(v0.y) + unp(v1.y);
            a2 += unp(v0.z) + unp(v1.z);
            a3 += unp(v0.w) + unp(v1.w);
        }
        if (e < end) {  // unified tail: up to 7 edges, 2 parallel masked loads
            int i0 = e + rowgrp, i1 = e + 4 + rowgrp;
            bool ok0 = i0 < end, ok1 = i1 < end;
            int s0 = esrc[ok0 ? i0 : end - 1];
            int s1 = esrc[ok1 ? i1 : end - 1];
            uint4v v0 = *(const uint4v*)(feat2 + (size_t)s0 * 64 + dimgrp * 4);
            uint4v v1 = *(const uint4v*)(feat2 + (size_t)s1 * 64 + dimgrp * 4);
            float m0 = ok0 ? 1.f : 0.f, m1 = ok1 ? 1.f : 0.f;
            float2v m0v = {m0, m0}, m1v = {m1, m1};
            a0 += m0v * unp(v0.x) + m1v * unp(v1.x);
            a1 += m0v * unp(v0.y) + m1v * unp(v1.y);
            a2 += m0v * unp(v0.z) + m1v * unp(v1.z);
            a3 += m0v * unp(v0.w) + m1v * unp(v1.w);
        }
        // reduce-scatter over rowgrp bits: lane keeps accumulator index == rowgrp.
        float2v s0v = (rowgrp & 1) ? a0 : a1;
        float2v k0v = (rowgrp & 1) ? a1 : a0;
        float2v s2v = (rowgrp & 1) ? a2 : a3;
        float2v k2v = (rowgrp & 1) ? a3 : a2;
        k0v.x += __shfl_xor(s0v.x, 16, 64);
        k0v.y += __shfl_xor(s0v.y, 16, 64);
        k2v.x += __shfl_xor(s2v.x, 16, 64);
        k2v.y += __shfl_xor(s2v.y, 16, 64);
        float2v sv = (rowgrp & 2) ? k0v : k2v;
        float2v kv = (rowgrp & 2) ? k2v : k0v;
        kv.x += __shfl_xor(sv.x, 32, 64);
        kv.y += __shfl_xor(sv.y, 32, 64);
        int deg = end - beg;
        float sc = deg > 0 ? 1.f / (float)deg : 0.f;
        meanout[(size_t)node * 64 + dimgrp * 4 + rowgrp] = packbf(kv.x * sc, kv.y * sc);
        if (nn >= N_NODES) break;
        node = nn;
        beg = nbg;
        end = nen;
    }
}

// ---- SAGE GEMM v9: v8 at 1024 threads -> 32 waves/CU ------------------------
// R7 inference: v8 <= 40.4 us (top-5 proof), moving ~125 MB => ~3.2 TB/s --
// the same occupancy-limited streaming signature as agg (R3: BW scales with
// waves/CU). v9 = v8 with 1024-thread blocks: 16 waves x 16-row tiles = 256
// rows/block, grid 391 (all resident, one pass); LDS 64 KB -> 2 blocks/CU =
// 32 waves/CU. launch_bounds(1024,8) -> 64-VGPR cap; measured need in this
// exact per-wave shape is 44 (R5/v7 counter), so no spill (R4 lesson checked,
// not hoped). Everything else identical to v8.
// FUSE_FC: epilogue out[row] = sum_col relu(h)[col]*wfc[col] + bfc (fp32).

template <int FUSE_FC>
__global__ __launch_bounds__(1024, 8) void gemm_kernel(
    const unsigned short* __restrict__ A0,  // mean rows
    const unsigned short* __restrict__ A1,  // self rows (xbf or h1)
    const unsigned int* __restrict__ Wpk,   // 2 matrices, mat m at dword m*8192
    const float* __restrict__ bias, const float* __restrict__ wfc,
    const float* __restrict__ bfc, unsigned short* __restrict__ hout,
    float* __restrict__ out) {
    __shared__ unsigned int wlds[16384];  // 64 KB: BOTH W matrices, frag-major

    int t = threadIdx.x;
    int wave = t >> 6, lane = t & 63;
    int lrow = lane & 15;   // A row-in-tile / B col-in-tile / C col
    int qsel = lane >> 4;   // k-octet select
    int rowBase = blockIdx.x * 256 + wave * 16;

    int rA = rowBase + lrow;
    if (rA >= N_NODES) rA = N_NODES - 1;  // clamp; masked at store

    // all 8 A-frags issued before staging: HBM latency hides under stage+barrier
    short8 am[4], as[4];
#pragma unroll
    for (int kt = 0; kt < 4; ++kt) {
        am[kt] = *(const short8*)(A0 + (size_t)rA * DIM + kt * 32 + qsel * 8);
        as[kt] = *(const short8*)(A1 + (size_t)rA * DIM + kt * 32 + qsel * 8);
    }

    {  // ---- stage BOTH mats: 1024 threads, 4 quads each ----
        int m = t >> 9, tid = t & 511;       // mat, 512 threads per mat
        int row = tid >> 2, qb = (tid & 3) * 4;  // row 0..127, quad base
        const unsigned int* g = Wpk + m * 8192 + row * 64 + qb * 4;
        unsigned int* l = wlds + m * 8192;
#pragma unroll
        for (int q = 0; q < 4; ++q) {
            uint4v v = *(const uint4v*)(g + q * 4);
            *(uint4v*)(l + (((qb + q) * 128 + row) << 2)) = v;
        }
    }
    __syncthreads();

    float4v acc[8];
#pragma unroll
    for (int nt = 0; nt < 8; ++nt) acc[nt] = (float4v){0.f, 0.f, 0.f, 0.f};

    // ---- steps 0-3: A = mean, B = W0 (LDS) ----
#pragma unroll
    for (int kt = 0; kt < 4; ++kt) {
        int qg = kt * 4 + qsel;
#pragma unroll
        for (int nt = 0; nt < 8; ++nt) {
            short8 b = *(const short8*)(wlds + ((qg * 128 + nt * 16 + lrow) << 2));
            acc[nt] = __builtin_amdgcn_mfma_f32_16x16x32_bf16(am[kt], b, acc[nt], 0, 0, 0);
        }
    }
    // ---- steps 4-7: A = self, B = W1 (LDS, second half) ----
#pragma unroll
    for (int kt = 0; kt < 4; ++kt) {
        int qg = kt * 4 + qsel;
#pragma unroll
        for (int nt = 0; nt < 8; ++nt) {
            short8 b = *(const short8*)(wlds + 8192 + ((qg * 128 + nt * 16 + lrow) << 2));
            acc[nt] = __builtin_amdgcn_mfma_f32_16x16x32_bf16(as[kt], b, acc[nt], 0, 0, 0);
        }
    }

    // ---- epilogue ----
    int crow0 = qsel * 4;
    if (!FUSE_FC) {
#pragma unroll
        for (int nt = 0; nt < 8; ++nt) {
            int col = nt * 16 + lrow;
            float bv = bias[col];
#pragma unroll
            for (int r4 = 0; r4 < 4; ++r4) {
                int row = rowBase + crow0 + r4;
                if (row < N_NODES) {
                    float v = acc[nt][r4] + bv;
                    hout[(size_t)row * DIM + col] = f2bf(v > 0.f ? v : 0.f);
                }
            }
        }
    } else {
        float bv[8], wv[8];
#pragma unroll
        for (int nt = 0; nt < 8; ++nt) {
            bv[nt] = bias[nt * 16 + lrow];
            wv[nt] = wfc[nt * 16 + lrow];
        }
        float bf0 = bfc[0];
#pragma unroll
        for (int r4 = 0; r4 < 4; ++r4) {
            float p = 0.f;
#pragma unroll
            for (int nt = 0; nt < 8; ++nt) {
                float v = acc[nt][r4] + bv[nt];
                p += (v > 0.f ? v : 0.f) * wv[nt];
            }
#pragma unroll
            for (int off = 1; off < 16; off <<= 1) p += __shfl_xor(p, off, 64);
            int row = rowBase + crow0 + r4;
            if (lrow == 0 && row < N_NODES) out[row] = p + bf0;
        }
    }
}

// ---- host glue -------------------------------------------------------------

extern "C" void kernel_launch(void* const* d_in, const int* in_sizes, int n_in,
                              void* d_out, int out_size, void* d_ws, size_t ws_size,
                              hipStream_t stream) {
    const float* x  = (const float*)d_in[0];
    const int* edge = (const int*)d_in[1];
    const float* W1l = (const float*)d_in[2];
    const float* b1  = (const float*)d_in[3];
    const float* W1r = (const float*)d_in[4];
    const float* W2l = (const float*)d_in[5];
    const float* b2  = (const float*)d_in[6];
    const float* W2r = (const float*)d_in[7];
    const float* Wfc = (const float*)d_in[8];
    const float* bfc = (const float*)d_in[9];
    float* out = (float*)d_out;  // fp32 output

    char* ws = (char*)d_ws;
    size_t off = 0;
    int* rowptr = (int*)(ws + off); off += ((size_t)N_NODES + 64) * 4;
    int* esrc   = (int*)(ws + off); off += (size_t)N_EDGES * 4;
    int* cur    = (int*)(ws + off); off += (size_t)NB * 4 + 256;
    off = (off + 255) & ~(size_t)255;
    unsigned int* pairs = (unsigned int*)(ws + off); off += (size_t)NB * BKCAP * 4;
    off = (off + 255) & ~(size_t)255;
    unsigned int* wbf = (unsigned int*)(ws + off); off += 4 * 8192 * 4;
    off = (off + 255) & ~(size_t)255;
    unsigned short* xbf  = (unsigned short*)(ws + off); off += (size_t)N_NODES * DIM * 2;
    unsigned short* mean = (unsigned short*)(ws + off); off += (size_t)N_NODES * DIM * 2;
    unsigned short* h1   = (unsigned short*)(ws + off); off += (size_t)N_NODES * DIM * 2;
    // total ~84 MB

    const int gemmBlocks = (N_NODES + 255) / 256;    // 391 (256 rows/block)
    const int convBlocks = (NXF + WF4 + 255) / 256;  // float4 units

    hipMemsetAsync(cur, 0, NB * sizeof(int), stream);
    binconv_kernel<<<BINB + convBlocks, 256, 0, stream>>>(edge, cur, pairs, x,
                                                          W1l, W1r, W2l, W2r,
                                                          (unsigned int*)xbf, wbf);
    csr_kernel<<<NB, 256, 0, stream>>>(cur, pairs, rowptr, esrc);

    // layer 1: W mats 0,1
    agg_kernel<<<2048, 256, 0, stream>>>((const unsigned int*)xbf, rowptr, esrc,
                                         (unsigned int*)mean);
    gemm_kernel<0><<<gemmBlocks, 1024, 0, stream>>>(mean, xbf, wbf, b1, nullptr, nullptr,
                                                    h1, nullptr);
    // layer 2 + fused FC: W mats 2,3
    agg_kernel<<<2048, 256, 0, stream>>>((const unsigned int*)h1, rowptr, esrc,
                                         (unsigned int*)mean);
    gemm_kernel<1><<<gemmBlocks, 1024, 0, stream>>>(mean, h1, wbf + 2 * 8192, b2, Wfc, bfc,
                                                    nullptr, out);
}